// Round 7
// baseline (1666.601 us; speedup 1.0000x reference)
//
#include <hip/hip_runtime.h>
#include <hip/hip_bf16.h>
#include <math.h>

// Problem dims (fixed by reference)
#define C_DIM 256      // h width
#define HID 128
#define HEADS 4
#define OC 64          // per-head out channels
#define FF_DIM 512
#define NLAYERS 12

constexpr float LN_EPS = 1e-5f;
constexpr float SLOPE  = 0.2f;

typedef __attribute__((ext_vector_type(4))) float f32x4;
typedef __attribute__((ext_vector_type(8))) short bf16x8_t;
typedef __attribute__((ext_vector_type(4))) int i32x4;

__device__ __forceinline__ float leaky(float x) { return x > 0.f ? x : SLOPE * x; }

__device__ __forceinline__ float bf2f(unsigned short u) {
    union { unsigned i; float f; } v; v.i = ((unsigned)u) << 16; return v.f;
}
__device__ __forceinline__ void bf2x(unsigned u, float& lo, float& hi) {
    union { unsigned i; float f; } a, b;
    a.i = u << 16; b.i = u & 0xffff0000u;
    lo = a.f; hi = b.f;
}
__device__ __forceinline__ unsigned packbf(float lo, float hi) {
    unsigned a = __bfloat16_as_ushort(__float2bfloat16(lo));
    unsigned b = __bfloat16_as_ushort(__float2bfloat16(hi));
    return a | (b << 16);
}

// ---------------------------------------------------------------------------
// Small utility kernels
// ---------------------------------------------------------------------------
__global__ void zero_i32_kernel(int* __restrict__ p, int n) {
    int i = blockIdx.x * blockDim.x + threadIdx.x;
    if (i < n) p[i] = 0;
}

__global__ void concat_kernel(const float* __restrict__ hf, const float* __restrict__ hs,
                              float* __restrict__ h, __hip_bfloat16* __restrict__ hb, int Nn) {
    int idx = blockIdx.x * blockDim.x + threadIdx.x;
    int total = Nn * C_DIM;
    if (idx < total) {
        int n = idx >> 8;
        int c = idx & 255;
        float v = (c < HID) ? hf[n * HID + c] : hs[n * HID + (c - HID)];
        h[idx] = v;
        hb[idx] = __float2bfloat16(v);
    }
}

// Transpose + convert weights: in [L][K][N] fp32 -> out [L][N][K] bf16
__global__ void transp_bf16_kernel(const float* __restrict__ in,
                                   __hip_bfloat16* __restrict__ out, int K, int N) {
    __shared__ float t[32][33];
    const float* inl = in + (size_t)blockIdx.z * K * N;
    __hip_bfloat16* outl = out + (size_t)blockIdx.z * K * N;
    int kb = blockIdx.y * 32, nb = blockIdx.x * 32;
    int tx = threadIdx.x & 31, ty = threadIdx.x >> 5; // 32x8
    #pragma unroll
    for (int r = 0; r < 32; r += 8)
        t[ty + r][tx] = inl[(size_t)(kb + ty + r) * N + nb + tx];
    __syncthreads();
    #pragma unroll
    for (int r = 0; r < 32; r += 8)
        outl[(size_t)(nb + ty + r) * K + kb + tx] = __float2bfloat16(t[tx][ty + r]);
}

// ---------------------------------------------------------------------------
// CSR build: histogram of dst, exclusive scan (wave-shuffle), fill src lists
// ---------------------------------------------------------------------------
__global__ void hist_kernel(const int* __restrict__ dst, int* __restrict__ counts, int E) {
    int e = blockIdx.x * blockDim.x + threadIdx.x;
    if (e < E) atomicAdd(&counts[dst[e]], 1);
}

// single block, 1024 threads = 16 waves. Wave shuffle scan + serial wave-sum scan.
__global__ void scan_kernel(const int* __restrict__ counts, int* __restrict__ offsets,
                            int* __restrict__ cursor, int n) {
    __shared__ int wsum[16];
    __shared__ int carry_s;
    const int lane = threadIdx.x & 63, wid = threadIdx.x >> 6;
    if (threadIdx.x == 0) carry_s = 0;
    __syncthreads();
    for (int base = 0; base < n; base += 1024) {
        int i = base + (int)threadIdx.x;
        int v = (i < n) ? counts[i] : 0;
        int x = v;
        #pragma unroll
        for (int off = 1; off < 64; off <<= 1) {
            int t = __shfl_up(x, off);
            if (lane >= off) x += t;
        }
        if (lane == 63) wsum[wid] = x;
        __syncthreads();
        if (threadIdx.x == 0) {
            int acc = carry_s;
            #pragma unroll
            for (int w = 0; w < 16; ++w) { int t = wsum[w]; wsum[w] = acc; acc += t; }
            carry_s = acc;
        }
        __syncthreads();
        int excl = wsum[wid] + x - v;
        if (i < n) { offsets[i] = excl; cursor[i] = excl; }
        __syncthreads();
    }
    if (threadIdx.x == 0) offsets[n] = carry_s;
}

__global__ void fill_kernel(const int* __restrict__ src, const int* __restrict__ dst,
                            int* __restrict__ cursor, int* __restrict__ csr_src, int E) {
    int e = blockIdx.x * blockDim.x + threadIdx.x;
    if (e < E) {
        int d = dst[e];
        int p = atomicAdd(&cursor[d], 1);
        csr_src[p] = src[e];
    }
}

// ---------------------------------------------------------------------------
// bf16 MFMA GEMM (used for GEMM1 only): 64x64 tile, BK=64, 256 thr.
// C/D: col=lane&15, row=(lane>>4)*4+reg  [verified m89/m91]
// Fused attention epilogue: BN=64 => one block covers one head's columns.
// ---------------------------------------------------------------------------
#define GBM 64
#define GBN 64
#define GBK 64
#define GLS 72   // LDS row stride (shorts): 144B; 2-way bank alias = free

__global__ __launch_bounds__(256) void gemm_bf16_kernel(
    const __hip_bfloat16* __restrict__ A,   // [M x K] bf16 row-major
    const __hip_bfloat16* __restrict__ BT,  // [N x K] bf16 row-major (B^T)
    const float* __restrict__ bias,         // [N] or null
    __hip_bfloat16* __restrict__ Cb,        // bf16 out
    const float* __restrict__ attS,         // [N] att_src slice or null
    const float* __restrict__ attD,
    float* __restrict__ aS,                 // [M x HEADS] out or null
    float* __restrict__ aD,
    int M, int N, int K, int relu)
{
    __shared__ short As[GBM * GLS];
    __shared__ short Bs[GBN * GLS];
    __shared__ float attP[2][2][GBM];       // [wn-half][s|d][row]
    const int tid = threadIdx.x;
    const int wave = tid >> 6, lane = tid & 63;
    const int lr = lane & 15, lq = lane >> 4;
    const int wm = (wave >> 1) * 32, wn = (wave & 1) * 32;
    const int row0 = blockIdx.x * GBM, col0 = blockIdx.y * GBN;

    const int sr = tid >> 2;              // staging row 0..63
    const int sc = (tid & 3) * 16;        // staging col (shorts): 0,16,32,48

    f32x4 acc[2][2] = {};

    for (int k0 = 0; k0 < K; k0 += GBK) {
        int gr = row0 + sr;
        i32x4 va0 = {}, va1 = {};
        if (gr < M) {
            const __hip_bfloat16* ap = &A[(size_t)gr * K + k0 + sc];
            va0 = *(const i32x4*)ap;
            va1 = *(const i32x4*)(ap + 8);
        }
        *(i32x4*)&As[sr * GLS + sc] = va0;
        *(i32x4*)&As[sr * GLS + sc + 8] = va1;
        const __hip_bfloat16* bp = &BT[(size_t)(col0 + sr) * K + k0 + sc];
        *(i32x4*)&Bs[sr * GLS + sc] = *(const i32x4*)bp;
        *(i32x4*)&Bs[sr * GLS + sc + 8] = *(const i32x4*)(bp + 8);
        __syncthreads();

        #pragma unroll
        for (int ks = 0; ks < 2; ++ks) {
            bf16x8_t af[2], bfr[2];
            #pragma unroll
            for (int t = 0; t < 2; ++t) {
                af[t]  = *(const bf16x8_t*)&As[(wm + t * 16 + lr) * GLS + ks * 32 + lq * 8];
                bfr[t] = *(const bf16x8_t*)&Bs[(wn + t * 16 + lr) * GLS + ks * 32 + lq * 8];
            }
            #pragma unroll
            for (int mt = 0; mt < 2; ++mt)
                #pragma unroll
                for (int nt = 0; nt < 2; ++nt)
                    acc[mt][nt] = __builtin_amdgcn_mfma_f32_16x16x32_bf16(
                        af[mt], bfr[nt], acc[mt][nt], 0, 0, 0);
        }
        __syncthreads();
    }

    float bv[2];
    #pragma unroll
    for (int nt = 0; nt < 2; ++nt)
        bv[nt] = bias ? bias[col0 + wn + nt * 16 + lr] : 0.f;

    #pragma unroll
    for (int mt = 0; mt < 2; ++mt) {
        #pragma unroll
        for (int r = 0; r < 4; ++r) {
            int grow = row0 + wm + mt * 16 + lq * 4 + r;
            if (grow >= M) continue;
            #pragma unroll
            for (int nt = 0; nt < 2; ++nt) {
                float v = acc[mt][nt][r] + bv[nt];
                if (relu) v = fmaxf(v, 0.f);
                Cb[(size_t)grow * N + col0 + wn + nt * 16 + lr] = __float2bfloat16(v);
            }
        }
    }

    // Fused attention-coefficient epilogue (gemm1 only)
    if (aS) {
        const int head = col0 >> 6;        // block covers one head (BN=64)
        float atS[2], atD[2];
        #pragma unroll
        for (int nt = 0; nt < 2; ++nt) {
            int c = col0 + wn + nt * 16 + lr;
            atS[nt] = attS[c];
            atD[nt] = attD[c];
        }
        #pragma unroll
        for (int mt = 0; mt < 2; ++mt) {
            #pragma unroll
            for (int r = 0; r < 4; ++r) {
                float vs = acc[mt][0][r] * atS[0] + acc[mt][1][r] * atS[1];
                float vd = acc[mt][0][r] * atD[0] + acc[mt][1][r] * atD[1];
                #pragma unroll
                for (int off = 1; off < 16; off <<= 1) {
                    vs += __shfl_xor(vs, off);
                    vd += __shfl_xor(vd, off);
                }
                if (lr == 0) {
                    int rl = wm + mt * 16 + lq * 4 + r;
                    attP[wave & 1][0][rl] = vs;
                    attP[wave & 1][1][rl] = vd;
                }
            }
        }
        __syncthreads();
        if (tid < GBM) {
            int grow = row0 + tid;
            if (grow < M) {
                aS[grow * HEADS + head] = attP[0][0][tid] + attP[1][0][tid];
                aD[grow * HEADS + head] = attP[0][1][tid] + attP[1][1][tid];
            }
        }
    }
}

// ---------------------------------------------------------------------------
// Fused GAT: per-edge exp weights in-loop + weighted bf16 gather + bias +
// residual + LN1. One WAVE per node; lane owns 8 channels (16B gathers);
// two 32-lane halves process disjoint edge subsets; combined via shfl_xor(32).
// ---------------------------------------------------------------------------
__global__ __launch_bounds__(256) void agg_kernel(
    const __hip_bfloat16* __restrict__ xhb, const float* __restrict__ a_s,
    const float* __restrict__ a_d, const int* __restrict__ csr,
    const int* __restrict__ offs, const float* __restrict__ gat_b,
    const float* __restrict__ ln_g, const float* __restrict__ ln_b,
    float* __restrict__ h, __hip_bfloat16* __restrict__ hb, int Nn)
{
    const int lane = threadIdx.x & 63;
    const int n = __builtin_amdgcn_readfirstlane(blockIdx.x * 4 + (threadIdx.x >> 6));
    if (n >= Nn) return;
    const int half = lane >> 5;
    const int sl = lane & 31;
    const int head = sl >> 3;            // 8 lanes per head
    const int c0 = sl * 8;               // 8 channels per lane
    const unsigned* x = (const unsigned*)xhb;   // packed bf16 pairs
    const size_t rowp = (size_t)n * (C_DIM / 2) + (c0 >> 1);

    const float ad = a_d[n * 4 + head];

    const int beg = offs[n], end = offs[n + 1];
    const int ne = end - beg;
    const int nh0 = (ne + 1) >> 1;
    int ih  = half ? (beg + nh0) : beg;
    int cnt = half ? (ne - nh0) : nh0;

    float acc[8] = {};
    float z = 0.f;

    {
        float wself = __expf(leaky(a_s[n * 4 + head] + ad));
        if (half) {
            i32x4 xv = *(const i32x4*)&x[rowp];
            #pragma unroll
            for (int q = 0; q < 4; ++q) {
                float lo, hi; bf2x((unsigned)xv[q], lo, hi);
                acc[2 * q]     = wself * lo;
                acc[2 * q + 1] = wself * hi;
            }
            z = wself;
        }
    }

    for (; cnt >= 4; cnt -= 4, ih += 4) {
        int s0 = csr[ih], s1 = csr[ih + 1], s2 = csr[ih + 2], s3 = csr[ih + 3];
        float w0 = __expf(leaky(a_s[s0 * 4 + head] + ad));
        float w1 = __expf(leaky(a_s[s1 * 4 + head] + ad));
        float w2 = __expf(leaky(a_s[s2 * 4 + head] + ad));
        float w3 = __expf(leaky(a_s[s3 * 4 + head] + ad));
        i32x4 x0 = *(const i32x4*)&x[(size_t)s0 * (C_DIM / 2) + (c0 >> 1)];
        i32x4 x1 = *(const i32x4*)&x[(size_t)s1 * (C_DIM / 2) + (c0 >> 1)];
        i32x4 x2 = *(const i32x4*)&x[(size_t)s2 * (C_DIM / 2) + (c0 >> 1)];
        i32x4 x3 = *(const i32x4*)&x[(size_t)s3 * (C_DIM / 2) + (c0 >> 1)];
        #pragma unroll
        for (int q = 0; q < 4; ++q) {
            float lo, hi;
            bf2x((unsigned)x0[q], lo, hi);
            acc[2 * q] += w0 * lo; acc[2 * q + 1] += w0 * hi;
            bf2x((unsigned)x1[q], lo, hi);
            acc[2 * q] += w1 * lo; acc[2 * q + 1] += w1 * hi;
            bf2x((unsigned)x2[q], lo, hi);
            acc[2 * q] += w2 * lo; acc[2 * q + 1] += w2 * hi;
            bf2x((unsigned)x3[q], lo, hi);
            acc[2 * q] += w3 * lo; acc[2 * q + 1] += w3 * hi;
        }
        z += (w0 + w1) + (w2 + w3);
    }
    for (; cnt > 0; --cnt, ++ih) {
        int s0 = csr[ih];
        float w0 = __expf(leaky(a_s[s0 * 4 + head] + ad));
        i32x4 x0 = *(const i32x4*)&x[(size_t)s0 * (C_DIM / 2) + (c0 >> 1)];
        #pragma unroll
        for (int q = 0; q < 4; ++q) {
            float lo, hi; bf2x((unsigned)x0[q], lo, hi);
            acc[2 * q] += w0 * lo; acc[2 * q + 1] += w0 * hi;
        }
        z += w0;
    }

    #pragma unroll
    for (int j = 0; j < 8; ++j) acc[j] += __shfl_xor(acc[j], 32);
    z += __shfl_xor(z, 32);

    float4 res0 = *(const float4*)&h[(size_t)n * C_DIM + c0];
    float4 res1 = *(const float4*)&h[(size_t)n * C_DIM + c0 + 4];
    float4 gb0 = *(const float4*)&gat_b[c0];
    float4 gb1 = *(const float4*)&gat_b[c0 + 4];
    float rz = 1.0f / z;
    float val[8];
    val[0] = acc[0] * rz + gb0.x + res0.x;
    val[1] = acc[1] * rz + gb0.y + res0.y;
    val[2] = acc[2] * rz + gb0.z + res0.z;
    val[3] = acc[3] * rz + gb0.w + res0.w;
    val[4] = acc[4] * rz + gb1.x + res1.x;
    val[5] = acc[5] * rz + gb1.y + res1.y;
    val[6] = acc[6] * rz + gb1.z + res1.z;
    val[7] = acc[7] * rz + gb1.w + res1.w;

    // LN: each channel appears on 2 lanes -> normalize by 512.
    float s1 = 0.f, s2 = 0.f;
    #pragma unroll
    for (int j = 0; j < 8; ++j) { s1 += val[j]; s2 += val[j] * val[j]; }
    #pragma unroll
    for (int off = 1; off < 64; off <<= 1) {
        s1 += __shfl_xor(s1, off);
        s2 += __shfl_xor(s2, off);
    }
    float mean = s1 * (1.0f / (2 * C_DIM));
    float inv = rsqrtf(s2 * (1.0f / (2 * C_DIM)) - mean * mean + LN_EPS);

    if (half == 0) {
        float4 g0 = *(const float4*)&ln_g[c0];
        float4 g1 = *(const float4*)&ln_g[c0 + 4];
        float4 bb0 = *(const float4*)&ln_b[c0];
        float4 bb1 = *(const float4*)&ln_b[c0 + 4];
        float o[8];
        o[0] = (val[0] - mean) * inv * g0.x + bb0.x;
        o[1] = (val[1] - mean) * inv * g0.y + bb0.y;
        o[2] = (val[2] - mean) * inv * g0.z + bb0.z;
        o[3] = (val[3] - mean) * inv * g0.w + bb0.w;
        o[4] = (val[4] - mean) * inv * g1.x + bb1.x;
        o[5] = (val[5] - mean) * inv * g1.y + bb1.y;
        o[6] = (val[6] - mean) * inv * g1.z + bb1.z;
        o[7] = (val[7] - mean) * inv * g1.w + bb1.w;
        float4 o0 = {o[0], o[1], o[2], o[3]};
        float4 o1 = {o[4], o[5], o[6], o[7]};
        *(float4*)&h[(size_t)n * C_DIM + c0] = o0;
        *(float4*)&h[(size_t)n * C_DIM + c0 + 4] = o1;
        i32x4 ob;
        ob[0] = (int)packbf(o[0], o[1]);
        ob[1] = (int)packbf(o[2], o[3]);
        ob[2] = (int)packbf(o[4], o[5]);
        ob[3] = (int)packbf(o[6], o[7]);
        *(i32x4*)&((unsigned*)hb)[rowp] = ob;
    }
}

// ---------------------------------------------------------------------------
// Fused FFN: h = LN( relu(hb@w1+b1)@w2 + b2 + h ).
// Block = 32 rows, 256 thr (4 waves). A(h rows) staged once in LDS; B-frags
// read DIRECTLY from global (w1T/w2T are 256KB L2-resident slabs reused by
// all 625 blocks) -> no per-iter staging barriers. mid (bf16) lives in LDS
// (padded rows, 2-way conflicts only). Per-row LN via 16-lane shfl partials
// + cross-wave LDS combine. Final layer writes split fp32 output.
// LDS: Ah 16.9KB + Mid 33.3KB + Red 1KB = 51.2KB -> 3 blocks/CU.
// ---------------------------------------------------------------------------
#define FBM 32
#define FPAD 264   // Ah row stride (shorts) = 256+8
#define MPAD 520   // Mid row stride (shorts) = 512+8

__global__ __launch_bounds__(256) void ffn_kernel(
    const __hip_bfloat16* __restrict__ hbin,  // [N x 256] bf16
    const __hip_bfloat16* __restrict__ w1T,   // [512 x 256] bf16
    const float* __restrict__ b1,             // [512]
    const __hip_bfloat16* __restrict__ w2T,   // [256 x 512] bf16
    const float* __restrict__ b2,             // [256]
    const float* __restrict__ ln_g, const float* __restrict__ ln_b,
    float* __restrict__ h, __hip_bfloat16* __restrict__ hbout,
    float* __restrict__ out_split, int Nn)
{
    __shared__ short Ah[FBM * FPAD];
    __shared__ short Mid[FBM * MPAD];
    __shared__ float Red[4][FBM][2];
    const int tid = threadIdx.x;
    const int wave = tid >> 6, lane = tid & 63;
    const int lr = lane & 15, lq = lane >> 4;
    const int row0 = blockIdx.x * FBM;     // Nn % 32 == 0 (20000)

    // Stage h rows (bf16) into LDS: 32x256 shorts = 1024 16B chunks, 4/thread
    #pragma unroll
    for (int c = 0; c < 4; ++c) {
        int chunk = tid + c * 256;
        int r = chunk >> 5, col = (chunk & 31) * 8;
        i32x4 v = *(const i32x4*)&hbin[(size_t)(row0 + r) * C_DIM + col];
        *(i32x4*)&Ah[r * FPAD + col] = v;
    }
    __syncthreads();

    // ---- Stage 1: mid = relu(Ah @ w1 + b1); wave owns FF cols [wave*128,+128)
    const int fcol0 = wave * 128;
    f32x4 acc1[2][8] = {};
    for (int k0 = 0; k0 < C_DIM; k0 += 32) {
        bf16x8_t af0 = *(const bf16x8_t*)&Ah[(lr) * FPAD + k0 + lq * 8];
        bf16x8_t af1 = *(const bf16x8_t*)&Ah[(16 + lr) * FPAD + k0 + lq * 8];
        #pragma unroll
        for (int nt = 0; nt < 8; ++nt) {
            bf16x8_t bf = *(const bf16x8_t*)&w1T[(size_t)(fcol0 + nt * 16 + lr) * C_DIM + k0 + lq * 8];
            acc1[0][nt] = __builtin_amdgcn_mfma_f32_16x16x32_bf16(af0, bf, acc1[0][nt], 0, 0, 0);
            acc1[1][nt] = __builtin_amdgcn_mfma_f32_16x16x32_bf16(af1, bf, acc1[1][nt], 0, 0, 0);
        }
    }
    // bias + relu + write mid (bf16) to LDS
    #pragma unroll
    for (int nt = 0; nt < 8; ++nt) {
        float bv = b1[fcol0 + nt * 16 + lr];
        #pragma unroll
        for (int mt = 0; mt < 2; ++mt)
            #pragma unroll
            for (int r = 0; r < 4; ++r) {
                float v = fmaxf(acc1[mt][nt][r] + bv, 0.f);
                Mid[(mt * 16 + lq * 4 + r) * MPAD + fcol0 + nt * 16 + lr] =
                    (short)__bfloat16_as_ushort(__float2bfloat16(v));
            }
    }
    __syncthreads();

    // ---- Stage 2: fb = Mid @ w2 + b2; wave owns C cols [wave*64,+64)
    const int ccol0 = wave * 64;
    f32x4 acc2[2][4] = {};
    for (int k0 = 0; k0 < FF_DIM; k0 += 32) {
        bf16x8_t af0 = *(const bf16x8_t*)&Mid[(lr) * MPAD + k0 + lq * 8];
        bf16x8_t af1 = *(const bf16x8_t*)&Mid[(16 + lr) * MPAD + k0 + lq * 8];
        #pragma unroll
        for (int nt = 0; nt < 4; ++nt) {
            bf16x8_t bf = *(const bf16x8_t*)&w2T[(size_t)(ccol0 + nt * 16 + lr) * FF_DIM + k0 + lq * 8];
            acc2[0][nt] = __builtin_amdgcn_mfma_f32_16x16x32_bf16(af0, bf, acc2[0][nt], 0, 0, 0);
            acc2[1][nt] = __builtin_amdgcn_mfma_f32_16x16x32_bf16(af1, bf, acc2[1][nt], 0, 0, 0);
        }
    }

    // ---- Stage 3: + b2 + residual, per-row LN over 256 cols
    float b2v[4];
    #pragma unroll
    for (int nt = 0; nt < 4; ++nt) b2v[nt] = b2[ccol0 + nt * 16 + lr];

    float vals[2][4][4];
    #pragma unroll
    for (int mt = 0; mt < 2; ++mt)
        #pragma unroll
        for (int r = 0; r < 4; ++r) {
            int rowg = row0 + mt * 16 + lq * 4 + r;
            float ps1 = 0.f, ps2 = 0.f;
            #pragma unroll
            for (int nt = 0; nt < 4; ++nt) {
                float v = acc2[mt][nt][r] + b2v[nt] +
                          h[(size_t)rowg * C_DIM + ccol0 + nt * 16 + lr];
                vals[mt][nt][r] = v;
                ps1 += v;
                ps2 += v * v;
            }
            #pragma unroll
            for (int off = 1; off < 16; off <<= 1) {
                ps1 += __shfl_xor(ps1, off);
                ps2 += __shfl_xor(ps2, off);
            }
            if (lr == 0) {
                Red[wave][mt * 16 + lq * 4 + r][0] = ps1;
                Red[wave][mt * 16 + lq * 4 + r][1] = ps2;
            }
        }
    __syncthreads();

    float gv[4], bbv[4];
    #pragma unroll
    for (int nt = 0; nt < 4; ++nt) {
        gv[nt]  = ln_g[ccol0 + nt * 16 + lr];
        bbv[nt] = ln_b[ccol0 + nt * 16 + lr];
    }
    #pragma unroll
    for (int mt = 0; mt < 2; ++mt)
        #pragma unroll
        for (int r = 0; r < 4; ++r) {
            int rl = mt * 16 + lq * 4 + r;
            int rowg = row0 + rl;
            float s1 = Red[0][rl][0] + Red[1][rl][0] + Red[2][rl][0] + Red[3][rl][0];
            float s2 = Red[0][rl][1] + Red[1][rl][1] + Red[2][rl][1] + Red[3][rl][1];
            float mean = s1 * (1.0f / C_DIM);
            float inv = rsqrtf(s2 * (1.0f / C_DIM) - mean * mean + LN_EPS);
            #pragma unroll
            for (int nt = 0; nt < 4; ++nt) {
                int col = ccol0 + nt * 16 + lr;
                float o = (vals[mt][nt][r] - mean) * inv * gv[nt] + bbv[nt];
                if (out_split) {
                    size_t off_ = (col < HID) ? ((size_t)rowg * HID + col)
                                              : ((size_t)Nn * HID + (size_t)rowg * HID + (col - HID));
                    out_split[off_] = o;
                } else {
                    h[(size_t)rowg * C_DIM + col] = o;
                    hbout[(size_t)rowg * C_DIM + col] = __float2bfloat16(o);
                }
            }
        }
}

// ---------------------------------------------------------------------------
// Host launch
// ---------------------------------------------------------------------------
extern "C" void kernel_launch(void* const* d_in, const int* in_sizes, int n_in,
                              void* d_out, int out_size, void* d_ws, size_t ws_size,
                              hipStream_t stream)
{
    const float* hf       = (const float*)d_in[0];
    const float* hs       = (const float*)d_in[1];
    const int*   edge     = (const int*)  d_in[2];
    const float* W        = (const float*)d_in[3];
    const float* att_src  = (const float*)d_in[4];
    const float* att_dst  = (const float*)d_in[5];
    const float* gat_b    = (const float*)d_in[6];
    const float* w1       = (const float*)d_in[7];
    const float* b1       = (const float*)d_in[8];
    const float* w2       = (const float*)d_in[9];
    const float* b2       = (const float*)d_in[10];
    const float* ln1g     = (const float*)d_in[11];
    const float* ln1b     = (const float*)d_in[12];
    const float* ln2g     = (const float*)d_in[13];
    const float* ln2b     = (const float*)d_in[14];
    float* out = (float*)d_out;

    const int N = in_sizes[0] / HID;       // 20000
    const int E = in_sizes[2] / 2;         // 320000
    const int* e_src = edge;
    const int* e_dst = edge + E;

    char* p = (char*)d_ws;
    auto alloc = [&](size_t bytes) {
        char* r = p;
        p += (bytes + 255) & ~(size_t)255;
        return (void*)r;
    };
    float*          h      = (float*)alloc((size_t)N * C_DIM * 4);
    __hip_bfloat16* hb     = (__hip_bfloat16*)alloc((size_t)N * C_DIM * 2);
    __hip_bfloat16* xhb    = (__hip_bfloat16*)alloc((size_t)N * C_DIM * 2);  // gemm1 out
    float*          a_s    = (float*)alloc((size_t)N * HEADS * 4);
    float*          a_d    = (float*)alloc((size_t)N * HEADS * 4);
    int*            counts = (int*)alloc((size_t)N * 4);
    int*            offs   = (int*)alloc((size_t)(N + 1) * 4);
    int*            cursor = (int*)alloc((size_t)N * 4);
    int*            csr    = (int*)alloc((size_t)E * 4);
    __hip_bfloat16* WT     = (__hip_bfloat16*)alloc((size_t)NLAYERS * C_DIM * C_DIM * 2);
    __hip_bfloat16* w1T    = (__hip_bfloat16*)alloc((size_t)NLAYERS * C_DIM * FF_DIM * 2);
    __hip_bfloat16* w2T    = (__hip_bfloat16*)alloc((size_t)NLAYERS * FF_DIM * C_DIM * 2);

    {
        int total = N * C_DIM;
        concat_kernel<<<(total + 255) / 256, 256, 0, stream>>>(hf, hs, h, hb, N);
    }
    transp_bf16_kernel<<<dim3(C_DIM / 32, C_DIM / 32, NLAYERS), 256, 0, stream>>>(W, WT, C_DIM, C_DIM);
    transp_bf16_kernel<<<dim3(FF_DIM / 32, C_DIM / 32, NLAYERS), 256, 0, stream>>>(w1, w1T, C_DIM, FF_DIM);
    transp_bf16_kernel<<<dim3(C_DIM / 32, FF_DIM / 32, NLAYERS), 256, 0, stream>>>(w2, w2T, FF_DIM, C_DIM);

    zero_i32_kernel<<<(N + 255) / 256, 256, 0, stream>>>(counts, N);
    hist_kernel<<<(E + 255) / 256, 256, 0, stream>>>(e_dst, counts, E);
    scan_kernel<<<1, 1024, 0, stream>>>(counts, offs, cursor, N);
    fill_kernel<<<(E + 255) / 256, 256, 0, stream>>>(e_src, e_dst, cursor, csr, E);

    const int gm = (N + GBM - 1) / GBM;   // 313
    const int fm = N / FBM;               // 625

    for (int l = 0; l < NLAYERS; ++l) {
        const __hip_bfloat16* Wl  = WT  + (size_t)l * C_DIM * C_DIM;
        const __hip_bfloat16* w1l = w1T + (size_t)l * C_DIM * FF_DIM;
        const __hip_bfloat16* w2l = w2T + (size_t)l * FF_DIM * C_DIM;
        const float* asl  = att_src + (size_t)l * C_DIM;
        const float* adl  = att_dst + (size_t)l * C_DIM;
        const float* gbl  = gat_b + (size_t)l * C_DIM;
        const float* b1l  = b1 + (size_t)l * FF_DIM;
        const float* b2l  = b2 + (size_t)l * C_DIM;
        const float* g1l  = ln1g + (size_t)l * C_DIM;
        const float* be1l = ln1b + (size_t)l * C_DIM;
        const float* g2l  = ln2g + (size_t)l * C_DIM;
        const float* be2l = ln2b + (size_t)l * C_DIM;

        // xhb = h @ W[l] (bf16 out) + fused a_s/a_d epilogue
        gemm_bf16_kernel<<<dim3(gm, C_DIM / GBN), 256, 0, stream>>>(
            hb, Wl, nullptr, xhb, asl, adl, a_s, a_d, N, C_DIM, C_DIM, 0);
        // fused exp-weights + softmax-agg + bias + residual + LN1 (h, hb in place)
        agg_kernel<<<(N + 3) / 4, 256, 0, stream>>>(
            xhb, a_s, a_d, csr, offs, gbl, g1l, be1l, h, hb, N);
        // fused FFN: h = LN(relu(hb@w1+b1)@w2 + b2 + h); last layer -> split out
        ffn_kernel<<<fm, 256, 0, stream>>>(
            hb, w1l, b1l, w2l, b2l, g2l, be2l, h, hb,
            (l == NLAYERS - 1) ? out : nullptr, N);
    }
}

// Round 8
// 1316.176 us; speedup vs baseline: 1.2662x; 1.2662x over previous
//
#include <hip/hip_runtime.h>
#include <hip/hip_bf16.h>
#include <math.h>

// Problem dims (fixed by reference)
#define C_DIM 256      // h width
#define HID 128
#define HEADS 4
#define OC 64          // per-head out channels
#define FF_DIM 512
#define NLAYERS 12

constexpr float LN_EPS = 1e-5f;
constexpr float SLOPE  = 0.2f;

typedef __attribute__((ext_vector_type(4))) float f32x4;
typedef __attribute__((ext_vector_type(8))) short bf16x8_t;
typedef __attribute__((ext_vector_type(4))) int i32x4;

__device__ __forceinline__ float leaky(float x) { return x > 0.f ? x : SLOPE * x; }

__device__ __forceinline__ float bf2f(unsigned short u) {
    union { unsigned i; float f; } v; v.i = ((unsigned)u) << 16; return v.f;
}
__device__ __forceinline__ void bf2x(unsigned u, float& lo, float& hi) {
    union { unsigned i; float f; } a, b;
    a.i = u << 16; b.i = u & 0xffff0000u;
    lo = a.f; hi = b.f;
}
__device__ __forceinline__ unsigned packbf(float lo, float hi) {
    unsigned a = __bfloat16_as_ushort(__float2bfloat16(lo));
    unsigned b = __bfloat16_as_ushort(__float2bfloat16(hi));
    return a | (b << 16);
}

// ---------------------------------------------------------------------------
// Small utility kernels
// ---------------------------------------------------------------------------
__global__ void zero_i32_kernel(int* __restrict__ p, int n) {
    int i = blockIdx.x * blockDim.x + threadIdx.x;
    if (i < n) p[i] = 0;
}

__global__ void concat_kernel(const float* __restrict__ hf, const float* __restrict__ hs,
                              float* __restrict__ h, __hip_bfloat16* __restrict__ hb, int Nn) {
    int idx = blockIdx.x * blockDim.x + threadIdx.x;
    int total = Nn * C_DIM;
    if (idx < total) {
        int n = idx >> 8;
        int c = idx & 255;
        float v = (c < HID) ? hf[n * HID + c] : hs[n * HID + (c - HID)];
        h[idx] = v;
        hb[idx] = __float2bfloat16(v);
    }
}

// Transpose + convert weights: in [L][K][N] fp32 -> out [L][N][K] bf16
__global__ void transp_bf16_kernel(const float* __restrict__ in,
                                   __hip_bfloat16* __restrict__ out, int K, int N) {
    __shared__ float t[32][33];
    const float* inl = in + (size_t)blockIdx.z * K * N;
    __hip_bfloat16* outl = out + (size_t)blockIdx.z * K * N;
    int kb = blockIdx.y * 32, nb = blockIdx.x * 32;
    int tx = threadIdx.x & 31, ty = threadIdx.x >> 5; // 32x8
    #pragma unroll
    for (int r = 0; r < 32; r += 8)
        t[ty + r][tx] = inl[(size_t)(kb + ty + r) * N + nb + tx];
    __syncthreads();
    #pragma unroll
    for (int r = 0; r < 32; r += 8)
        outl[(size_t)(nb + ty + r) * K + kb + tx] = __float2bfloat16(t[tx][ty + r]);
}

// ---------------------------------------------------------------------------
// CSR build: histogram of dst, exclusive scan (wave-shuffle), fill src lists
// ---------------------------------------------------------------------------
__global__ void hist_kernel(const int* __restrict__ dst, int* __restrict__ counts, int E) {
    int e = blockIdx.x * blockDim.x + threadIdx.x;
    if (e < E) atomicAdd(&counts[dst[e]], 1);
}

// single block, 1024 threads = 16 waves. Wave shuffle scan + serial wave-sum scan.
__global__ void scan_kernel(const int* __restrict__ counts, int* __restrict__ offsets,
                            int* __restrict__ cursor, int n) {
    __shared__ int wsum[16];
    __shared__ int carry_s;
    const int lane = threadIdx.x & 63, wid = threadIdx.x >> 6;
    if (threadIdx.x == 0) carry_s = 0;
    __syncthreads();
    for (int base = 0; base < n; base += 1024) {
        int i = base + (int)threadIdx.x;
        int v = (i < n) ? counts[i] : 0;
        int x = v;
        #pragma unroll
        for (int off = 1; off < 64; off <<= 1) {
            int t = __shfl_up(x, off);
            if (lane >= off) x += t;
        }
        if (lane == 63) wsum[wid] = x;
        __syncthreads();
        if (threadIdx.x == 0) {
            int acc = carry_s;
            #pragma unroll
            for (int w = 0; w < 16; ++w) { int t = wsum[w]; wsum[w] = acc; acc += t; }
            carry_s = acc;
        }
        __syncthreads();
        int excl = wsum[wid] + x - v;
        if (i < n) { offsets[i] = excl; cursor[i] = excl; }
        __syncthreads();
    }
    if (threadIdx.x == 0) offsets[n] = carry_s;
}

__global__ void fill_kernel(const int* __restrict__ src, const int* __restrict__ dst,
                            int* __restrict__ cursor, int* __restrict__ csr_src, int E) {
    int e = blockIdx.x * blockDim.x + threadIdx.x;
    if (e < E) {
        int d = dst[e];
        int p = atomicAdd(&cursor[d], 1);
        csr_src[p] = src[e];
    }
}

// ---------------------------------------------------------------------------
// bf16 MFMA GEMM: 64x64 tile, BK=64, 256 thr (2x2 waves, 32x32 per wave).
// C/D: col=lane&15, row=(lane>>4)*4+reg  [verified m89/m91]
// Fused attention epilogue: BN=64 => one block covers one head's columns.
// ---------------------------------------------------------------------------
#define GBM 64
#define GBN 64
#define GBK 64
#define GLS 72   // LDS row stride (shorts): 144B; 2-way bank alias = free

__global__ __launch_bounds__(256) void gemm_bf16_kernel(
    const __hip_bfloat16* __restrict__ A,   // [M x K] bf16 row-major
    const __hip_bfloat16* __restrict__ BT,  // [N x K] bf16 row-major (B^T)
    const float* __restrict__ bias,         // [N] or null
    __hip_bfloat16* __restrict__ Cb,        // bf16 out
    const float* __restrict__ attS,         // [N] att_src slice or null
    const float* __restrict__ attD,
    float* __restrict__ aS,                 // [M x HEADS] out or null
    float* __restrict__ aD,
    int M, int N, int K, int relu)
{
    __shared__ short As[GBM * GLS];
    __shared__ short Bs[GBN * GLS];
    __shared__ float attP[2][2][GBM];       // [wn-half][s|d][row]
    const int tid = threadIdx.x;
    const int wave = tid >> 6, lane = tid & 63;
    const int lr = lane & 15, lq = lane >> 4;
    const int wm = (wave >> 1) * 32, wn = (wave & 1) * 32;
    const int row0 = blockIdx.x * GBM, col0 = blockIdx.y * GBN;

    const int sr = tid >> 2;              // staging row 0..63
    const int sc = (tid & 3) * 16;        // staging col (shorts): 0,16,32,48

    f32x4 acc[2][2] = {};

    for (int k0 = 0; k0 < K; k0 += GBK) {
        int gr = row0 + sr;
        i32x4 va0 = {}, va1 = {};
        if (gr < M) {
            const __hip_bfloat16* ap = &A[(size_t)gr * K + k0 + sc];
            va0 = *(const i32x4*)ap;
            va1 = *(const i32x4*)(ap + 8);
        }
        *(i32x4*)&As[sr * GLS + sc] = va0;
        *(i32x4*)&As[sr * GLS + sc + 8] = va1;
        const __hip_bfloat16* bp = &BT[(size_t)(col0 + sr) * K + k0 + sc];
        *(i32x4*)&Bs[sr * GLS + sc] = *(const i32x4*)bp;
        *(i32x4*)&Bs[sr * GLS + sc + 8] = *(const i32x4*)(bp + 8);
        __syncthreads();

        #pragma unroll
        for (int ks = 0; ks < 2; ++ks) {
            bf16x8_t af[2], bfr[2];
            #pragma unroll
            for (int t = 0; t < 2; ++t) {
                af[t]  = *(const bf16x8_t*)&As[(wm + t * 16 + lr) * GLS + ks * 32 + lq * 8];
                bfr[t] = *(const bf16x8_t*)&Bs[(wn + t * 16 + lr) * GLS + ks * 32 + lq * 8];
            }
            #pragma unroll
            for (int mt = 0; mt < 2; ++mt)
                #pragma unroll
                for (int nt = 0; nt < 2; ++nt)
                    acc[mt][nt] = __builtin_amdgcn_mfma_f32_16x16x32_bf16(
                        af[mt], bfr[nt], acc[mt][nt], 0, 0, 0);
        }
        __syncthreads();
    }

    float bv[2];
    #pragma unroll
    for (int nt = 0; nt < 2; ++nt)
        bv[nt] = bias ? bias[col0 + wn + nt * 16 + lr] : 0.f;

    #pragma unroll
    for (int mt = 0; mt < 2; ++mt) {
        #pragma unroll
        for (int r = 0; r < 4; ++r) {
            int grow = row0 + wm + mt * 16 + lq * 4 + r;
            if (grow >= M) continue;
            #pragma unroll
            for (int nt = 0; nt < 2; ++nt) {
                float v = acc[mt][nt][r] + bv[nt];
                if (relu) v = fmaxf(v, 0.f);
                Cb[(size_t)grow * N + col0 + wn + nt * 16 + lr] = __float2bfloat16(v);
            }
        }
    }

    // Fused attention-coefficient epilogue (gemm1 only)
    if (aS) {
        const int head = col0 >> 6;        // block covers one head (BN=64)
        float atS[2], atD[2];
        #pragma unroll
        for (int nt = 0; nt < 2; ++nt) {
            int c = col0 + wn + nt * 16 + lr;
            atS[nt] = attS[c];
            atD[nt] = attD[c];
        }
        #pragma unroll
        for (int mt = 0; mt < 2; ++mt) {
            #pragma unroll
            for (int r = 0; r < 4; ++r) {
                float vs = acc[mt][0][r] * atS[0] + acc[mt][1][r] * atS[1];
                float vd = acc[mt][0][r] * atD[0] + acc[mt][1][r] * atD[1];
                #pragma unroll
                for (int off = 1; off < 16; off <<= 1) {
                    vs += __shfl_xor(vs, off);
                    vd += __shfl_xor(vd, off);
                }
                if (lr == 0) {
                    int rl = wm + mt * 16 + lq * 4 + r;
                    attP[wave & 1][0][rl] = vs;
                    attP[wave & 1][1][rl] = vd;
                }
            }
        }
        __syncthreads();
        if (tid < GBM) {
            int grow = row0 + tid;
            if (grow < M) {
                aS[grow * HEADS + head] = attP[0][0][tid] + attP[1][0][tid];
                aD[grow * HEADS + head] = attP[0][1][tid] + attP[1][1][tid];
            }
        }
    }
}

// ---------------------------------------------------------------------------
// Fused GAT: per-edge exp weights in-loop + weighted bf16 gather + bias +
// residual + LN1. TWO WAVES per node (2 nodes / 256-block); each wave's two
// 32-lane halves process disjoint edge quarters (serial chain ~ne/4);
// lane owns 8 channels (16B gathers). Cross-wave combine via 4KB LDS + one
// barrier (node index clamped, never early-return, so barrier is uniform).
// ---------------------------------------------------------------------------
__global__ __launch_bounds__(256) void agg_kernel(
    const __hip_bfloat16* __restrict__ xhb, const float* __restrict__ a_s,
    const float* __restrict__ a_d, const int* __restrict__ csr,
    const int* __restrict__ offs, const float* __restrict__ gat_b,
    const float* __restrict__ ln_g, const float* __restrict__ ln_b,
    float* __restrict__ h, __hip_bfloat16* __restrict__ hb, int Nn)
{
    __shared__ float part[2][2][C_DIM];   // [node][wave-in-node][channel]
    __shared__ float zpart[2][2][HEADS];
    const int tid = threadIdx.x;
    const int lane = tid & 63;
    const int nd = tid >> 7;              // node slot 0/1
    const int wv = (tid >> 6) & 1;        // wave within node
    int n_raw = blockIdx.x * 2 + nd;
    const int n = __builtin_amdgcn_readfirstlane(n_raw < Nn ? n_raw : Nn - 1);
    const int half = lane >> 5;
    const int sl = lane & 31;
    const int head = sl >> 3;             // 8 lanes per head
    const int c0 = sl * 8;                // 8 channels per lane
    const int quarter = wv * 2 + half;    // 0..3
    const unsigned* x = (const unsigned*)xhb;   // packed bf16 pairs
    const size_t rowp = (size_t)n * (C_DIM / 2) + (c0 >> 1);

    const float ad = a_d[n * 4 + head];

    const int beg = offs[n], end = offs[n + 1];
    const int ne = end - beg;
    int ih  = beg + ((ne * quarter) >> 2);
    int cnt = (beg + ((ne * (quarter + 1)) >> 2)) - ih;

    float acc[8] = {};
    float z = 0.f;

    // self-loop handled by quarter 3
    if (quarter == 3) {
        float wself = __expf(leaky(a_s[n * 4 + head] + ad));
        i32x4 xv = *(const i32x4*)&x[rowp];
        #pragma unroll
        for (int q = 0; q < 4; ++q) {
            float lo, hi; bf2x((unsigned)xv[q], lo, hi);
            acc[2 * q]     = wself * lo;
            acc[2 * q + 1] = wself * hi;
        }
        z = wself;
    }

    for (; cnt >= 4; cnt -= 4, ih += 4) {
        int s0 = csr[ih], s1 = csr[ih + 1], s2 = csr[ih + 2], s3 = csr[ih + 3];
        float w0 = __expf(leaky(a_s[s0 * 4 + head] + ad));
        float w1 = __expf(leaky(a_s[s1 * 4 + head] + ad));
        float w2 = __expf(leaky(a_s[s2 * 4 + head] + ad));
        float w3 = __expf(leaky(a_s[s3 * 4 + head] + ad));
        i32x4 x0 = *(const i32x4*)&x[(size_t)s0 * (C_DIM / 2) + (c0 >> 1)];
        i32x4 x1 = *(const i32x4*)&x[(size_t)s1 * (C_DIM / 2) + (c0 >> 1)];
        i32x4 x2 = *(const i32x4*)&x[(size_t)s2 * (C_DIM / 2) + (c0 >> 1)];
        i32x4 x3 = *(const i32x4*)&x[(size_t)s3 * (C_DIM / 2) + (c0 >> 1)];
        #pragma unroll
        for (int q = 0; q < 4; ++q) {
            float lo, hi;
            bf2x((unsigned)x0[q], lo, hi);
            acc[2 * q] += w0 * lo; acc[2 * q + 1] += w0 * hi;
            bf2x((unsigned)x1[q], lo, hi);
            acc[2 * q] += w1 * lo; acc[2 * q + 1] += w1 * hi;
            bf2x((unsigned)x2[q], lo, hi);
            acc[2 * q] += w2 * lo; acc[2 * q + 1] += w2 * hi;
            bf2x((unsigned)x3[q], lo, hi);
            acc[2 * q] += w3 * lo; acc[2 * q + 1] += w3 * hi;
        }
        z += (w0 + w1) + (w2 + w3);
    }
    for (; cnt > 0; --cnt, ++ih) {
        int s0 = csr[ih];
        float w0 = __expf(leaky(a_s[s0 * 4 + head] + ad));
        i32x4 x0 = *(const i32x4*)&x[(size_t)s0 * (C_DIM / 2) + (c0 >> 1)];
        #pragma unroll
        for (int q = 0; q < 4; ++q) {
            float lo, hi; bf2x((unsigned)x0[q], lo, hi);
            acc[2 * q] += w0 * lo; acc[2 * q + 1] += w0 * hi;
        }
        z += w0;
    }

    // combine the two halves within the wave
    #pragma unroll
    for (int j = 0; j < 8; ++j) acc[j] += __shfl_xor(acc[j], 32);
    z += __shfl_xor(z, 32);

    // publish wave partials (half 0 holds the combined values)
    if (half == 0) {
        #pragma unroll
        for (int j = 0; j < 8; ++j) part[nd][wv][c0 + j] = acc[j];
        if ((sl & 7) == 0) zpart[nd][wv][head] = z;
    }
    __syncthreads();

    // cross-wave combine (both waves compute; wave 0 writes)
    float accT[8];
    #pragma unroll
    for (int j = 0; j < 8; ++j)
        accT[j] = part[nd][0][c0 + j] + part[nd][1][c0 + j];
    float zT = zpart[nd][0][head] + zpart[nd][1][head];

    float4 res0 = *(const float4*)&h[(size_t)n * C_DIM + c0];
    float4 res1 = *(const float4*)&h[(size_t)n * C_DIM + c0 + 4];
    float4 gb0 = *(const float4*)&gat_b[c0];
    float4 gb1 = *(const float4*)&gat_b[c0 + 4];
    float rz = 1.0f / zT;
    float val[8];
    val[0] = accT[0] * rz + gb0.x + res0.x;
    val[1] = accT[1] * rz + gb0.y + res0.y;
    val[2] = accT[2] * rz + gb0.z + res0.z;
    val[3] = accT[3] * rz + gb0.w + res0.w;
    val[4] = accT[4] * rz + gb1.x + res1.x;
    val[5] = accT[5] * rz + gb1.y + res1.y;
    val[6] = accT[6] * rz + gb1.z + res1.z;
    val[7] = accT[7] * rz + gb1.w + res1.w;

    // LN: channels duplicated across the 2 halves -> normalize by 512.
    float s1 = 0.f, s2 = 0.f;
    #pragma unroll
    for (int j = 0; j < 8; ++j) { s1 += val[j]; s2 += val[j] * val[j]; }
    #pragma unroll
    for (int off = 1; off < 64; off <<= 1) {
        s1 += __shfl_xor(s1, off);
        s2 += __shfl_xor(s2, off);
    }
    float mean = s1 * (1.0f / (2 * C_DIM));
    float inv = rsqrtf(s2 * (1.0f / (2 * C_DIM)) - mean * mean + LN_EPS);

    if (wv == 0 && half == 0 && n_raw < Nn) {
        float4 g0 = *(const float4*)&ln_g[c0];
        float4 g1 = *(const float4*)&ln_g[c0 + 4];
        float4 bb0 = *(const float4*)&ln_b[c0];
        float4 bb1 = *(const float4*)&ln_b[c0 + 4];
        float o[8];
        o[0] = (val[0] - mean) * inv * g0.x + bb0.x;
        o[1] = (val[1] - mean) * inv * g0.y + bb0.y;
        o[2] = (val[2] - mean) * inv * g0.z + bb0.z;
        o[3] = (val[3] - mean) * inv * g0.w + bb0.w;
        o[4] = (val[4] - mean) * inv * g1.x + bb1.x;
        o[5] = (val[5] - mean) * inv * g1.y + bb1.y;
        o[6] = (val[6] - mean) * inv * g1.z + bb1.z;
        o[7] = (val[7] - mean) * inv * g1.w + bb1.w;
        float4 o0 = {o[0], o[1], o[2], o[3]};
        float4 o1 = {o[4], o[5], o[6], o[7]};
        *(float4*)&h[(size_t)n * C_DIM + c0] = o0;
        *(float4*)&h[(size_t)n * C_DIM + c0 + 4] = o1;
        i32x4 ob;
        ob[0] = (int)packbf(o[0], o[1]);
        ob[1] = (int)packbf(o[2], o[3]);
        ob[2] = (int)packbf(o[4], o[5]);
        ob[3] = (int)packbf(o[6], o[7]);
        *(i32x4*)&((unsigned*)hb)[rowp] = ob;
    }
}

// ---------------------------------------------------------------------------
// ln2: val = bf2f(fb) + h; LN; writes h+hb, or (final layer) split fp32 out.
// ---------------------------------------------------------------------------
__global__ __launch_bounds__(256) void ln2_kernel(
    const __hip_bfloat16* __restrict__ fb, const float* __restrict__ ln_g,
    const float* __restrict__ ln_b, float* __restrict__ h,
    __hip_bfloat16* __restrict__ hb, float* __restrict__ out_split, int Nn)
{
    const int lane = threadIdx.x & 63;
    const int n = __builtin_amdgcn_readfirstlane(blockIdx.x * 4 + (threadIdx.x >> 6));
    if (n >= Nn) return;
    const int c0 = lane * 4;
    const unsigned short* f = (const unsigned short*)fb;

    float4 res = *(const float4*)&h[(size_t)n * C_DIM + c0];
    ushort4 fv = *(const ushort4*)&f[(size_t)n * C_DIM + c0];
    float val[4];
    val[0] = bf2f(fv.x) + res.x;
    val[1] = bf2f(fv.y) + res.y;
    val[2] = bf2f(fv.z) + res.z;
    val[3] = bf2f(fv.w) + res.w;

    float s1 = (val[0] + val[1]) + (val[2] + val[3]);
    float s2 = (val[0] * val[0] + val[1] * val[1]) + (val[2] * val[2] + val[3] * val[3]);
    #pragma unroll
    for (int off = 1; off < 64; off <<= 1) {
        s1 += __shfl_xor(s1, off);
        s2 += __shfl_xor(s2, off);
    }
    float mean = s1 * (1.0f / C_DIM);
    float inv = rsqrtf(s2 * (1.0f / C_DIM) - mean * mean + LN_EPS);
    float4 g = *(const float4*)&ln_g[c0];
    float4 bb = *(const float4*)&ln_b[c0];
    float4 o;
    o.x = (val[0] - mean) * inv * g.x + bb.x;
    o.y = (val[1] - mean) * inv * g.y + bb.y;
    o.z = (val[2] - mean) * inv * g.z + bb.z;
    o.w = (val[3] - mean) * inv * g.w + bb.w;

    if (out_split) {
        size_t off_ = (c0 < HID) ? ((size_t)n * HID + c0)
                                 : ((size_t)Nn * HID + (size_t)n * HID + (c0 - HID));
        *(float4*)&out_split[off_] = o;
    } else {
        *(float4*)&h[(size_t)n * C_DIM + c0] = o;
        ushort4 ob;
        ob.x = __bfloat16_as_ushort(__float2bfloat16(o.x));
        ob.y = __bfloat16_as_ushort(__float2bfloat16(o.y));
        ob.z = __bfloat16_as_ushort(__float2bfloat16(o.z));
        ob.w = __bfloat16_as_ushort(__float2bfloat16(o.w));
        *(ushort4*)&((unsigned short*)hb)[(size_t)n * C_DIM + c0] = ob;
    }
}

// ---------------------------------------------------------------------------
// Host launch
// ---------------------------------------------------------------------------
extern "C" void kernel_launch(void* const* d_in, const int* in_sizes, int n_in,
                              void* d_out, int out_size, void* d_ws, size_t ws_size,
                              hipStream_t stream)
{
    const float* hf       = (const float*)d_in[0];
    const float* hs       = (const float*)d_in[1];
    const int*   edge     = (const int*)  d_in[2];
    const float* W        = (const float*)d_in[3];
    const float* att_src  = (const float*)d_in[4];
    const float* att_dst  = (const float*)d_in[5];
    const float* gat_b    = (const float*)d_in[6];
    const float* w1       = (const float*)d_in[7];
    const float* b1       = (const float*)d_in[8];
    const float* w2       = (const float*)d_in[9];
    const float* b2       = (const float*)d_in[10];
    const float* ln1g     = (const float*)d_in[11];
    const float* ln1b     = (const float*)d_in[12];
    const float* ln2g     = (const float*)d_in[13];
    const float* ln2b     = (const float*)d_in[14];
    float* out = (float*)d_out;

    const int N = in_sizes[0] / HID;       // 20000
    const int E = in_sizes[2] / 2;         // 320000
    const int* e_src = edge;
    const int* e_dst = edge + E;

    char* p = (char*)d_ws;
    auto alloc = [&](size_t bytes) {
        char* r = p;
        p += (bytes + 255) & ~(size_t)255;
        return (void*)r;
    };
    float*          h      = (float*)alloc((size_t)N * C_DIM * 4);
    __hip_bfloat16* hb     = (__hip_bfloat16*)alloc((size_t)N * C_DIM * 2);
    __hip_bfloat16* xhb    = (__hip_bfloat16*)alloc((size_t)N * C_DIM * 2);  // gemm1 out
    __hip_bfloat16* fbuf   = (__hip_bfloat16*)alloc((size_t)N * C_DIM * 2);  // gemm3 out
    __hip_bfloat16* midb   = (__hip_bfloat16*)alloc((size_t)N * FF_DIM * 2);
    float*          a_s    = (float*)alloc((size_t)N * HEADS * 4);
    float*          a_d    = (float*)alloc((size_t)N * HEADS * 4);
    int*            counts = (int*)alloc((size_t)N * 4);
    int*            offs   = (int*)alloc((size_t)(N + 1) * 4);
    int*            cursor = (int*)alloc((size_t)N * 4);
    int*            csr    = (int*)alloc((size_t)E * 4);
    __hip_bfloat16* WT     = (__hip_bfloat16*)alloc((size_t)NLAYERS * C_DIM * C_DIM * 2);
    __hip_bfloat16* w1T    = (__hip_bfloat16*)alloc((size_t)NLAYERS * C_DIM * FF_DIM * 2);
    __hip_bfloat16* w2T    = (__hip_bfloat16*)alloc((size_t)NLAYERS * FF_DIM * C_DIM * 2);

    {
        int total = N * C_DIM;
        concat_kernel<<<(total + 255) / 256, 256, 0, stream>>>(hf, hs, h, hb, N);
    }
    transp_bf16_kernel<<<dim3(C_DIM / 32, C_DIM / 32, NLAYERS), 256, 0, stream>>>(W, WT, C_DIM, C_DIM);
    transp_bf16_kernel<<<dim3(FF_DIM / 32, C_DIM / 32, NLAYERS), 256, 0, stream>>>(w1, w1T, C_DIM, FF_DIM);
    transp_bf16_kernel<<<dim3(C_DIM / 32, FF_DIM / 32, NLAYERS), 256, 0, stream>>>(w2, w2T, FF_DIM, C_DIM);

    zero_i32_kernel<<<(N + 255) / 256, 256, 0, stream>>>(counts, N);
    hist_kernel<<<(E + 255) / 256, 256, 0, stream>>>(e_dst, counts, E);
    scan_kernel<<<1, 1024, 0, stream>>>(counts, offs, cursor, N);
    fill_kernel<<<(E + 255) / 256, 256, 0, stream>>>(e_src, e_dst, cursor, csr, E);

    const int gm = (N + GBM - 1) / GBM;   // 313

    for (int l = 0; l < NLAYERS; ++l) {
        const __hip_bfloat16* Wl  = WT  + (size_t)l * C_DIM * C_DIM;
        const __hip_bfloat16* w1l = w1T + (size_t)l * C_DIM * FF_DIM;
        const __hip_bfloat16* w2l = w2T + (size_t)l * FF_DIM * C_DIM;
        const float* asl  = att_src + (size_t)l * C_DIM;
        const float* adl  = att_dst + (size_t)l * C_DIM;
        const float* gbl  = gat_b + (size_t)l * C_DIM;
        const float* b1l  = b1 + (size_t)l * FF_DIM;
        const float* b2l  = b2 + (size_t)l * C_DIM;
        const float* g1l  = ln1g + (size_t)l * C_DIM;
        const float* be1l = ln1b + (size_t)l * C_DIM;
        const float* g2l  = ln2g + (size_t)l * C_DIM;
        const float* be2l = ln2b + (size_t)l * C_DIM;

        // xhb = h @ W[l] (bf16 out) + fused a_s/a_d epilogue
        gemm_bf16_kernel<<<dim3(gm, C_DIM / GBN), 256, 0, stream>>>(
            hb, Wl, nullptr, xhb, asl, adl, a_s, a_d, N, C_DIM, C_DIM, 0);
        // fused exp-weights + softmax-agg + bias + residual + LN1 (h, hb in place)
        agg_kernel<<<(N + 1) / 2, 256, 0, stream>>>(
            xhb, a_s, a_d, csr, offs, gbl, g1l, be1l, h, hb, N);
        // mid = relu(h @ w1 + b1)  (bf16 out)
        gemm_bf16_kernel<<<dim3(gm, FF_DIM / GBN), 256, 0, stream>>>(
            hb, w1l, b1l, midb, nullptr, nullptr, nullptr, nullptr,
            N, FF_DIM, C_DIM, 1);
        // fbuf = mid @ w2 + b2  (bf16 out)
        gemm_bf16_kernel<<<dim3(gm, C_DIM / GBN), 256, 0, stream>>>(
            midb, w2l, b2l, fbuf, nullptr, nullptr, nullptr, nullptr,
            N, C_DIM, FF_DIM, 0);
        // h = LN(fbuf + h); final layer writes split output directly
        ln2_kernel<<<(N + 3) / 4, 256, 0, stream>>>(
            fbuf, g2l, be2l, h, hb, (l == NLAYERS - 1) ? out : nullptr, N);
    }
}

// Round 9
// 1269.796 us; speedup vs baseline: 1.3125x; 1.0365x over previous
//
#include <hip/hip_runtime.h>
#include <hip/hip_bf16.h>
#include <math.h>

// Problem dims (fixed by reference)
#define C_DIM 256      // h width
#define HID 128
#define HEADS 4
#define OC 64          // per-head out channels
#define FF_DIM 512
#define NLAYERS 12

constexpr float LN_EPS = 1e-5f;
constexpr float SLOPE  = 0.2f;

typedef __attribute__((ext_vector_type(4))) float f32x4;
typedef __attribute__((ext_vector_type(8))) short bf16x8_t;
typedef __attribute__((ext_vector_type(4))) int i32x4;

__device__ __forceinline__ float leaky(float x) { return x > 0.f ? x : SLOPE * x; }

__device__ __forceinline__ float bf2f(unsigned short u) {
    union { unsigned i; float f; } v; v.i = ((unsigned)u) << 16; return v.f;
}
__device__ __forceinline__ void bf2x(unsigned u, float& lo, float& hi) {
    union { unsigned i; float f; } a, b;
    a.i = u << 16; b.i = u & 0xffff0000u;
    lo = a.f; hi = b.f;
}
__device__ __forceinline__ unsigned packbf(float lo, float hi) {
    unsigned a = __bfloat16_as_ushort(__float2bfloat16(lo));
    unsigned b = __bfloat16_as_ushort(__float2bfloat16(hi));
    return a | (b << 16);
}

// ---------------------------------------------------------------------------
// Small utility kernels
// ---------------------------------------------------------------------------
__global__ void zero_i32_kernel(int* __restrict__ p, int n) {
    int i = blockIdx.x * blockDim.x + threadIdx.x;
    if (i < n) p[i] = 0;
}

__global__ void concat_kernel(const float* __restrict__ hf, const float* __restrict__ hs,
                              float* __restrict__ h, __hip_bfloat16* __restrict__ hb, int Nn) {
    int idx = blockIdx.x * blockDim.x + threadIdx.x;
    int total = Nn * C_DIM;
    if (idx < total) {
        int n = idx >> 8;
        int c = idx & 255;
        float v = (c < HID) ? hf[n * HID + c] : hs[n * HID + (c - HID)];
        h[idx] = v;
        hb[idx] = __float2bfloat16(v);
    }
}

// Transpose + convert weights: in [L][K][N] fp32 -> out [L][N][K] bf16
__global__ void transp_bf16_kernel(const float* __restrict__ in,
                                   __hip_bfloat16* __restrict__ out, int K, int N) {
    __shared__ float t[32][33];
    const float* inl = in + (size_t)blockIdx.z * K * N;
    __hip_bfloat16* outl = out + (size_t)blockIdx.z * K * N;
    int kb = blockIdx.y * 32, nb = blockIdx.x * 32;
    int tx = threadIdx.x & 31, ty = threadIdx.x >> 5; // 32x8
    #pragma unroll
    for (int r = 0; r < 32; r += 8)
        t[ty + r][tx] = inl[(size_t)(kb + ty + r) * N + nb + tx];
    __syncthreads();
    #pragma unroll
    for (int r = 0; r < 32; r += 8)
        outl[(size_t)(nb + ty + r) * K + kb + tx] = __float2bfloat16(t[tx][ty + r]);
}

// ---------------------------------------------------------------------------
// CSR build: histogram of dst, exclusive scan (wave-shuffle), fill src lists
// ---------------------------------------------------------------------------
__global__ void hist_kernel(const int* __restrict__ dst, int* __restrict__ counts, int E) {
    int e = blockIdx.x * blockDim.x + threadIdx.x;
    if (e < E) atomicAdd(&counts[dst[e]], 1);
}

// single block, 1024 threads = 16 waves. Wave shuffle scan + serial wave-sum scan.
__global__ void scan_kernel(const int* __restrict__ counts, int* __restrict__ offsets,
                            int* __restrict__ cursor, int n) {
    __shared__ int wsum[16];
    __shared__ int carry_s;
    const int lane = threadIdx.x & 63, wid = threadIdx.x >> 6;
    if (threadIdx.x == 0) carry_s = 0;
    __syncthreads();
    for (int base = 0; base < n; base += 1024) {
        int i = base + (int)threadIdx.x;
        int v = (i < n) ? counts[i] : 0;
        int x = v;
        #pragma unroll
        for (int off = 1; off < 64; off <<= 1) {
            int t = __shfl_up(x, off);
            if (lane >= off) x += t;
        }
        if (lane == 63) wsum[wid] = x;
        __syncthreads();
        if (threadIdx.x == 0) {
            int acc = carry_s;
            #pragma unroll
            for (int w = 0; w < 16; ++w) { int t = wsum[w]; wsum[w] = acc; acc += t; }
            carry_s = acc;
        }
        __syncthreads();
        int excl = wsum[wid] + x - v;
        if (i < n) { offsets[i] = excl; cursor[i] = excl; }
        __syncthreads();
    }
    if (threadIdx.x == 0) offsets[n] = carry_s;
}

__global__ void fill_kernel(const int* __restrict__ src, const int* __restrict__ dst,
                            int* __restrict__ cursor, int* __restrict__ csr_src, int E) {
    int e = blockIdx.x * blockDim.x + threadIdx.x;
    if (e < E) {
        int d = dst[e];
        int p = atomicAdd(&cursor[d], 1);
        csr_src[p] = src[e];
    }
}

// ---------------------------------------------------------------------------
// bf16 MFMA GEMM: 64x64 tile, BK=64, 256 thr (2x2 waves, 32x32 per wave).
// Register-prefetch pipeline: k-tile t+1 is loaded into VGPRs while MFMAs
// for tile t run from LDS -> global staging latency overlaps compute.
// C/D: col=lane&15, row=(lane>>4)*4+reg  [verified m89/m91]
// Fused attention epilogue: BN=64 => one block covers one head's columns.
// ---------------------------------------------------------------------------
#define GBM 64
#define GBN 64
#define GBK 64
#define GLS 72   // LDS row stride (shorts): 144B; 2-way bank alias = free

__global__ __launch_bounds__(256) void gemm_bf16_kernel(
    const __hip_bfloat16* __restrict__ A,   // [M x K] bf16 row-major
    const __hip_bfloat16* __restrict__ BT,  // [N x K] bf16 row-major (B^T)
    const float* __restrict__ bias,         // [N] or null
    __hip_bfloat16* __restrict__ Cb,        // bf16 out
    const float* __restrict__ attS,         // [N] att_src slice or null
    const float* __restrict__ attD,
    float* __restrict__ aS,                 // [M x HEADS] out or null
    float* __restrict__ aD,
    int M, int N, int K, int relu)
{
    __shared__ short As[GBM * GLS];
    __shared__ short Bs[GBN * GLS];
    __shared__ float attP[2][2][GBM];       // [wn-half][s|d][row]
    const int tid = threadIdx.x;
    const int wave = tid >> 6, lane = tid & 63;
    const int lr = lane & 15, lq = lane >> 4;
    const int wm = (wave >> 1) * 32, wn = (wave & 1) * 32;
    const int row0 = blockIdx.x * GBM, col0 = blockIdx.y * GBN;

    const int sr = tid >> 2;              // staging row 0..63
    const int sc = (tid & 3) * 16;        // staging col (shorts): 0,16,32,48
    const int ar = row0 + sr;
    const bool a_ok = (ar < M);
    const __hip_bfloat16* aB = &A[(size_t)(a_ok ? ar : 0) * K + sc];
    const __hip_bfloat16* bB = &BT[(size_t)(col0 + sr) * K + sc];

    f32x4 acc[2][2] = {};
    i32x4 ra0, ra1, rb0, rb1;

    // prologue: load k-tile 0
    {
        ra0 = a_ok ? *(const i32x4*)aB : i32x4{};
        ra1 = a_ok ? *(const i32x4*)(aB + 8) : i32x4{};
        rb0 = *(const i32x4*)bB;
        rb1 = *(const i32x4*)(bB + 8);
    }

    for (int k0 = 0; k0 < K; k0 += GBK) {
        *(i32x4*)&As[sr * GLS + sc] = ra0;
        *(i32x4*)&As[sr * GLS + sc + 8] = ra1;
        *(i32x4*)&Bs[sr * GLS + sc] = rb0;
        *(i32x4*)&Bs[sr * GLS + sc + 8] = rb1;
        __syncthreads();

        // issue next-tile loads early; consumed after MFMA section
        if (k0 + GBK < K) {
            const __hip_bfloat16* ap = aB + k0 + GBK;
            const __hip_bfloat16* bp = bB + k0 + GBK;
            ra0 = a_ok ? *(const i32x4*)ap : i32x4{};
            ra1 = a_ok ? *(const i32x4*)(ap + 8) : i32x4{};
            rb0 = *(const i32x4*)bp;
            rb1 = *(const i32x4*)(bp + 8);
        }

        #pragma unroll
        for (int ks = 0; ks < 2; ++ks) {
            bf16x8_t af[2], bfr[2];
            #pragma unroll
            for (int t = 0; t < 2; ++t) {
                af[t]  = *(const bf16x8_t*)&As[(wm + t * 16 + lr) * GLS + ks * 32 + lq * 8];
                bfr[t] = *(const bf16x8_t*)&Bs[(wn + t * 16 + lr) * GLS + ks * 32 + lq * 8];
            }
            #pragma unroll
            for (int mt = 0; mt < 2; ++mt)
                #pragma unroll
                for (int nt = 0; nt < 2; ++nt)
                    acc[mt][nt] = __builtin_amdgcn_mfma_f32_16x16x32_bf16(
                        af[mt], bfr[nt], acc[mt][nt], 0, 0, 0);
        }
        __syncthreads();
    }

    float bv[2];
    #pragma unroll
    for (int nt = 0; nt < 2; ++nt)
        bv[nt] = bias ? bias[col0 + wn + nt * 16 + lr] : 0.f;

    #pragma unroll
    for (int mt = 0; mt < 2; ++mt) {
        #pragma unroll
        for (int r = 0; r < 4; ++r) {
            int grow = row0 + wm + mt * 16 + lq * 4 + r;
            if (grow >= M) continue;
            #pragma unroll
            for (int nt = 0; nt < 2; ++nt) {
                float v = acc[mt][nt][r] + bv[nt];
                if (relu) v = fmaxf(v, 0.f);
                Cb[(size_t)grow * N + col0 + wn + nt * 16 + lr] = __float2bfloat16(v);
            }
        }
    }

    // Fused attention-coefficient epilogue (gemm1 only)
    if (aS) {
        const int head = col0 >> 6;        // block covers one head (BN=64)
        float atS[2], atD[2];
        #pragma unroll
        for (int nt = 0; nt < 2; ++nt) {
            int c = col0 + wn + nt * 16 + lr;
            atS[nt] = attS[c];
            atD[nt] = attD[c];
        }
        #pragma unroll
        for (int mt = 0; mt < 2; ++mt) {
            #pragma unroll
            for (int r = 0; r < 4; ++r) {
                float vs = acc[mt][0][r] * atS[0] + acc[mt][1][r] * atS[1];
                float vd = acc[mt][0][r] * atD[0] + acc[mt][1][r] * atD[1];
                #pragma unroll
                for (int off = 1; off < 16; off <<= 1) {
                    vs += __shfl_xor(vs, off);
                    vd += __shfl_xor(vd, off);
                }
                if (lr == 0) {
                    int rl = wm + mt * 16 + lq * 4 + r;
                    attP[wave & 1][0][rl] = vs;
                    attP[wave & 1][1][rl] = vd;
                }
            }
        }
        __syncthreads();
        if (tid < GBM) {
            int grow = row0 + tid;
            if (grow < M) {
                aS[grow * HEADS + head] = attP[0][0][tid] + attP[1][0][tid];
                aD[grow * HEADS + head] = attP[0][1][tid] + attP[1][1][tid];
            }
        }
    }
}

// ---------------------------------------------------------------------------
// Fused GAT: per-edge exp weights in-loop + weighted bf16 gather + bias +
// residual + LN1. One WAVE per node (R5 form — best measured); lane owns 8
// channels (16B gathers); two 32-lane halves process disjoint edge halves;
// combined via shfl_xor(32). No LDS, no barriers.
// ---------------------------------------------------------------------------
__global__ __launch_bounds__(256) void agg_kernel(
    const __hip_bfloat16* __restrict__ xhb, const float* __restrict__ a_s,
    const float* __restrict__ a_d, const int* __restrict__ csr,
    const int* __restrict__ offs, const float* __restrict__ gat_b,
    const float* __restrict__ ln_g, const float* __restrict__ ln_b,
    float* __restrict__ h, __hip_bfloat16* __restrict__ hb, int Nn)
{
    const int lane = threadIdx.x & 63;
    const int n = __builtin_amdgcn_readfirstlane(blockIdx.x * 4 + (threadIdx.x >> 6));
    if (n >= Nn) return;
    const int half = lane >> 5;
    const int sl = lane & 31;
    const int head = sl >> 3;            // 8 lanes per head
    const int c0 = sl * 8;               // 8 channels per lane
    const unsigned* x = (const unsigned*)xhb;   // packed bf16 pairs
    const size_t rowp = (size_t)n * (C_DIM / 2) + (c0 >> 1);

    const float ad = a_d[n * 4 + head];

    const int beg = offs[n], end = offs[n + 1];
    const int ne = end - beg;
    const int nh0 = (ne + 1) >> 1;
    int ih  = half ? (beg + nh0) : beg;
    int cnt = half ? (ne - nh0) : nh0;

    float acc[8] = {};
    float z = 0.f;

    {
        float wself = __expf(leaky(a_s[n * 4 + head] + ad));
        if (half) {
            i32x4 xv = *(const i32x4*)&x[rowp];
            #pragma unroll
            for (int q = 0; q < 4; ++q) {
                float lo, hi; bf2x((unsigned)xv[q], lo, hi);
                acc[2 * q]     = wself * lo;
                acc[2 * q + 1] = wself * hi;
            }
            z = wself;
        }
    }

    for (; cnt >= 4; cnt -= 4, ih += 4) {
        int s0 = csr[ih], s1 = csr[ih + 1], s2 = csr[ih + 2], s3 = csr[ih + 3];
        float w0 = __expf(leaky(a_s[s0 * 4 + head] + ad));
        float w1 = __expf(leaky(a_s[s1 * 4 + head] + ad));
        float w2 = __expf(leaky(a_s[s2 * 4 + head] + ad));
        float w3 = __expf(leaky(a_s[s3 * 4 + head] + ad));
        i32x4 x0 = *(const i32x4*)&x[(size_t)s0 * (C_DIM / 2) + (c0 >> 1)];
        i32x4 x1 = *(const i32x4*)&x[(size_t)s1 * (C_DIM / 2) + (c0 >> 1)];
        i32x4 x2 = *(const i32x4*)&x[(size_t)s2 * (C_DIM / 2) + (c0 >> 1)];
        i32x4 x3 = *(const i32x4*)&x[(size_t)s3 * (C_DIM / 2) + (c0 >> 1)];
        #pragma unroll
        for (int q = 0; q < 4; ++q) {
            float lo, hi;
            bf2x((unsigned)x0[q], lo, hi);
            acc[2 * q] += w0 * lo; acc[2 * q + 1] += w0 * hi;
            bf2x((unsigned)x1[q], lo, hi);
            acc[2 * q] += w1 * lo; acc[2 * q + 1] += w1 * hi;
            bf2x((unsigned)x2[q], lo, hi);
            acc[2 * q] += w2 * lo; acc[2 * q + 1] += w2 * hi;
            bf2x((unsigned)x3[q], lo, hi);
            acc[2 * q] += w3 * lo; acc[2 * q + 1] += w3 * hi;
        }
        z += (w0 + w1) + (w2 + w3);
    }
    for (; cnt > 0; --cnt, ++ih) {
        int s0 = csr[ih];
        float w0 = __expf(leaky(a_s[s0 * 4 + head] + ad));
        i32x4 x0 = *(const i32x4*)&x[(size_t)s0 * (C_DIM / 2) + (c0 >> 1)];
        #pragma unroll
        for (int q = 0; q < 4; ++q) {
            float lo, hi; bf2x((unsigned)x0[q], lo, hi);
            acc[2 * q] += w0 * lo; acc[2 * q + 1] += w0 * hi;
        }
        z += w0;
    }

    #pragma unroll
    for (int j = 0; j < 8; ++j) acc[j] += __shfl_xor(acc[j], 32);
    z += __shfl_xor(z, 32);

    float4 res0 = *(const float4*)&h[(size_t)n * C_DIM + c0];
    float4 res1 = *(const float4*)&h[(size_t)n * C_DIM + c0 + 4];
    float4 gb0 = *(const float4*)&gat_b[c0];
    float4 gb1 = *(const float4*)&gat_b[c0 + 4];
    float rz = 1.0f / z;
    float val[8];
    val[0] = acc[0] * rz + gb0.x + res0.x;
    val[1] = acc[1] * rz + gb0.y + res0.y;
    val[2] = acc[2] * rz + gb0.z + res0.z;
    val[3] = acc[3] * rz + gb0.w + res0.w;
    val[4] = acc[4] * rz + gb1.x + res1.x;
    val[5] = acc[5] * rz + gb1.y + res1.y;
    val[6] = acc[6] * rz + gb1.z + res1.z;
    val[7] = acc[7] * rz + gb1.w + res1.w;

    // LN: each channel appears on 2 lanes -> normalize by 512.
    float s1 = 0.f, s2 = 0.f;
    #pragma unroll
    for (int j = 0; j < 8; ++j) { s1 += val[j]; s2 += val[j] * val[j]; }
    #pragma unroll
    for (int off = 1; off < 64; off <<= 1) {
        s1 += __shfl_xor(s1, off);
        s2 += __shfl_xor(s2, off);
    }
    float mean = s1 * (1.0f / (2 * C_DIM));
    float inv = rsqrtf(s2 * (1.0f / (2 * C_DIM)) - mean * mean + LN_EPS);

    if (half == 0) {
        float4 g0 = *(const float4*)&ln_g[c0];
        float4 g1 = *(const float4*)&ln_g[c0 + 4];
        float4 bb0 = *(const float4*)&ln_b[c0];
        float4 bb1 = *(const float4*)&ln_b[c0 + 4];
        float o[8];
        o[0] = (val[0] - mean) * inv * g0.x + bb0.x;
        o[1] = (val[1] - mean) * inv * g0.y + bb0.y;
        o[2] = (val[2] - mean) * inv * g0.z + bb0.z;
        o[3] = (val[3] - mean) * inv * g0.w + bb0.w;
        o[4] = (val[4] - mean) * inv * g1.x + bb1.x;
        o[5] = (val[5] - mean) * inv * g1.y + bb1.y;
        o[6] = (val[6] - mean) * inv * g1.z + bb1.z;
        o[7] = (val[7] - mean) * inv * g1.w + bb1.w;
        float4 o0 = {o[0], o[1], o[2], o[3]};
        float4 o1 = {o[4], o[5], o[6], o[7]};
        *(float4*)&h[(size_t)n * C_DIM + c0] = o0;
        *(float4*)&h[(size_t)n * C_DIM + c0 + 4] = o1;
        i32x4 ob;
        ob[0] = (int)packbf(o[0], o[1]);
        ob[1] = (int)packbf(o[2], o[3]);
        ob[2] = (int)packbf(o[4], o[5]);
        ob[3] = (int)packbf(o[6], o[7]);
        *(i32x4*)&((unsigned*)hb)[rowp] = ob;
    }
}

// ---------------------------------------------------------------------------
// ln2: val = bf2f(fb) + h; LN; writes h+hb, or (final layer) split fp32 out.
// ---------------------------------------------------------------------------
__global__ __launch_bounds__(256) void ln2_kernel(
    const __hip_bfloat16* __restrict__ fb, const float* __restrict__ ln_g,
    const float* __restrict__ ln_b, float* __restrict__ h,
    __hip_bfloat16* __restrict__ hb, float* __restrict__ out_split, int Nn)
{
    const int lane = threadIdx.x & 63;
    const int n = __builtin_amdgcn_readfirstlane(blockIdx.x * 4 + (threadIdx.x >> 6));
    if (n >= Nn) return;
    const int c0 = lane * 4;
    const unsigned short* f = (const unsigned short*)fb;

    float4 res = *(const float4*)&h[(size_t)n * C_DIM + c0];
    ushort4 fv = *(const ushort4*)&f[(size_t)n * C_DIM + c0];
    float val[4];
    val[0] = bf2f(fv.x) + res.x;
    val[1] = bf2f(fv.y) + res.y;
    val[2] = bf2f(fv.z) + res.z;
    val[3] = bf2f(fv.w) + res.w;

    float s1 = (val[0] + val[1]) + (val[2] + val[3]);
    float s2 = (val[0] * val[0] + val[1] * val[1]) + (val[2] * val[2] + val[3] * val[3]);
    #pragma unroll
    for (int off = 1; off < 64; off <<= 1) {
        s1 += __shfl_xor(s1, off);
        s2 += __shfl_xor(s2, off);
    }
    float mean = s1 * (1.0f / C_DIM);
    float inv = rsqrtf(s2 * (1.0f / C_DIM) - mean * mean + LN_EPS);
    float4 g = *(const float4*)&ln_g[c0];
    float4 bb = *(const float4*)&ln_b[c0];
    float4 o;
    o.x = (val[0] - mean) * inv * g.x + bb.x;
    o.y = (val[1] - mean) * inv * g.y + bb.y;
    o.z = (val[2] - mean) * inv * g.z + bb.z;
    o.w = (val[3] - mean) * inv * g.w + bb.w;

    if (out_split) {
        size_t off_ = (c0 < HID) ? ((size_t)n * HID + c0)
                                 : ((size_t)Nn * HID + (size_t)n * HID + (c0 - HID));
        *(float4*)&out_split[off_] = o;
    } else {
        *(float4*)&h[(size_t)n * C_DIM + c0] = o;
        ushort4 ob;
        ob.x = __bfloat16_as_ushort(__float2bfloat16(o.x));
        ob.y = __bfloat16_as_ushort(__float2bfloat16(o.y));
        ob.z = __bfloat16_as_ushort(__float2bfloat16(o.z));
        ob.w = __bfloat16_as_ushort(__float2bfloat16(o.w));
        *(ushort4*)&((unsigned short*)hb)[(size_t)n * C_DIM + c0] = ob;
    }
}

// ---------------------------------------------------------------------------
// Host launch
// ---------------------------------------------------------------------------
extern "C" void kernel_launch(void* const* d_in, const int* in_sizes, int n_in,
                              void* d_out, int out_size, void* d_ws, size_t ws_size,
                              hipStream_t stream)
{
    const float* hf       = (const float*)d_in[0];
    const float* hs       = (const float*)d_in[1];
    const int*   edge     = (const int*)  d_in[2];
    const float* W        = (const float*)d_in[3];
    const float* att_src  = (const float*)d_in[4];
    const float* att_dst  = (const float*)d_in[5];
    const float* gat_b    = (const float*)d_in[6];
    const float* w1       = (const float*)d_in[7];
    const float* b1       = (const float*)d_in[8];
    const float* w2       = (const float*)d_in[9];
    const float* b2       = (const float*)d_in[10];
    const float* ln1g     = (const float*)d_in[11];
    const float* ln1b     = (const float*)d_in[12];
    const float* ln2g     = (const float*)d_in[13];
    const float* ln2b     = (const float*)d_in[14];
    float* out = (float*)d_out;

    const int N = in_sizes[0] / HID;       // 20000
    const int E = in_sizes[2] / 2;         // 320000
    const int* e_src = edge;
    const int* e_dst = edge + E;

    char* p = (char*)d_ws;
    auto alloc = [&](size_t bytes) {
        char* r = p;
        p += (bytes + 255) & ~(size_t)255;
        return (void*)r;
    };
    float*          h      = (float*)alloc((size_t)N * C_DIM * 4);
    __hip_bfloat16* hb     = (__hip_bfloat16*)alloc((size_t)N * C_DIM * 2);
    __hip_bfloat16* xhb    = (__hip_bfloat16*)alloc((size_t)N * C_DIM * 2);  // gemm1 out
    __hip_bfloat16* fbuf   = (__hip_bfloat16*)alloc((size_t)N * C_DIM * 2);  // gemm3 out
    __hip_bfloat16* midb   = (__hip_bfloat16*)alloc((size_t)N * FF_DIM * 2);
    float*          a_s    = (float*)alloc((size_t)N * HEADS * 4);
    float*          a_d    = (float*)alloc((size_t)N * HEADS * 4);
    int*            counts = (int*)alloc((size_t)N * 4);
    int*            offs   = (int*)alloc((size_t)(N + 1) * 4);
    int*            cursor = (int*)alloc((size_t)N * 4);
    int*            csr    = (int*)alloc((size_t)E * 4);
    __hip_bfloat16* WT     = (__hip_bfloat16*)alloc((size_t)NLAYERS * C_DIM * C_DIM * 2);
    __hip_bfloat16* w1T    = (__hip_bfloat16*)alloc((size_t)NLAYERS * C_DIM * FF_DIM * 2);
    __hip_bfloat16* w2T    = (__hip_bfloat16*)alloc((size_t)NLAYERS * FF_DIM * C_DIM * 2);

    {
        int total = N * C_DIM;
        concat_kernel<<<(total + 255) / 256, 256, 0, stream>>>(hf, hs, h, hb, N);
    }
    transp_bf16_kernel<<<dim3(C_DIM / 32, C_DIM / 32, NLAYERS), 256, 0, stream>>>(W, WT, C_DIM, C_DIM);
    transp_bf16_kernel<<<dim3(FF_DIM / 32, C_DIM / 32, NLAYERS), 256, 0, stream>>>(w1, w1T, C_DIM, FF_DIM);
    transp_bf16_kernel<<<dim3(C_DIM / 32, FF_DIM / 32, NLAYERS), 256, 0, stream>>>(w2, w2T, FF_DIM, C_DIM);

    zero_i32_kernel<<<(N + 255) / 256, 256, 0, stream>>>(counts, N);
    hist_kernel<<<(E + 255) / 256, 256, 0, stream>>>(e_dst, counts, E);
    scan_kernel<<<1, 1024, 0, stream>>>(counts, offs, cursor, N);
    fill_kernel<<<(E + 255) / 256, 256, 0, stream>>>(e_src, e_dst, cursor, csr, E);

    const int gm = (N + GBM - 1) / GBM;   // 313

    for (int l = 0; l < NLAYERS; ++l) {
        const __hip_bfloat16* Wl  = WT  + (size_t)l * C_DIM * C_DIM;
        const __hip_bfloat16* w1l = w1T + (size_t)l * C_DIM * FF_DIM;
        const __hip_bfloat16* w2l = w2T + (size_t)l * FF_DIM * C_DIM;
        const float* asl  = att_src + (size_t)l * C_DIM;
        const float* adl  = att_dst + (size_t)l * C_DIM;
        const float* gbl  = gat_b + (size_t)l * C_DIM;
        const float* b1l  = b1 + (size_t)l * FF_DIM;
        const float* b2l  = b2 + (size_t)l * C_DIM;
        const float* g1l  = ln1g + (size_t)l * C_DIM;
        const float* be1l = ln1b + (size_t)l * C_DIM;
        const float* g2l  = ln2g + (size_t)l * C_DIM;
        const float* be2l = ln2b + (size_t)l * C_DIM;

        // xhb = h @ W[l] (bf16 out) + fused a_s/a_d epilogue
        gemm_bf16_kernel<<<dim3(gm, C_DIM / GBN), 256, 0, stream>>>(
            hb, Wl, nullptr, xhb, asl, adl, a_s, a_d, N, C_DIM, C_DIM, 0);
        // fused exp-weights + softmax-agg + bias + residual + LN1 (h, hb in place)
        agg_kernel<<<(N + 3) / 4, 256, 0, stream>>>(
            xhb, a_s, a_d, csr, offs, gbl, g1l, be1l, h, hb, N);
        // mid = relu(h @ w1 + b1)  (bf16 out)
        gemm_bf16_kernel<<<dim3(gm, FF_DIM / GBN), 256, 0, stream>>>(
            hb, w1l, b1l, midb, nullptr, nullptr, nullptr, nullptr,
            N, FF_DIM, C_DIM, 1);
        // fbuf = mid @ w2 + b2  (bf16 out)
        gemm_bf16_kernel<<<dim3(gm, C_DIM / GBN), 256, 0, stream>>>(
            midb, w2l, b2l, fbuf, nullptr, nullptr, nullptr, nullptr,
            N, C_DIM, FF_DIM, 0);
        // h = LN(fbuf + h); final layer writes split output directly
        ln2_kernel<<<(N + 3) / 4, 256, 0, stream>>>(
            fbuf, g2l, be2l, h, hb, (l == NLAYERS - 1) ? out : nullptr, N);
    }
}

// Round 10
// 1229.641 us; speedup vs baseline: 1.3554x; 1.0327x over previous
//
#include <hip/hip_runtime.h>
#include <hip/hip_bf16.h>
#include <math.h>

// Problem dims (fixed by reference)
#define C_DIM 256      // h width
#define HID 128
#define HEADS 4
#define OC 64          // per-head out channels
#define FF_DIM 512
#define NLAYERS 12

constexpr float LN_EPS = 1e-5f;
constexpr float SLOPE  = 0.2f;

typedef __attribute__((ext_vector_type(4))) float f32x4;
typedef __attribute__((ext_vector_type(8))) short bf16x8_t;
typedef __attribute__((ext_vector_type(4))) int i32x4;

__device__ __forceinline__ float leaky(float x) { return x > 0.f ? x : SLOPE * x; }

__device__ __forceinline__ float bf2f(unsigned short u) {
    union { unsigned i; float f; } v; v.i = ((unsigned)u) << 16; return v.f;
}
__device__ __forceinline__ void bf2x(unsigned u, float& lo, float& hi) {
    union { unsigned i; float f; } a, b;
    a.i = u << 16; b.i = u & 0xffff0000u;
    lo = a.f; hi = b.f;
}
__device__ __forceinline__ unsigned packbf(float lo, float hi) {
    unsigned a = __bfloat16_as_ushort(__float2bfloat16(lo));
    unsigned b = __bfloat16_as_ushort(__float2bfloat16(hi));
    return a | (b << 16);
}

// ---------------------------------------------------------------------------
// Small utility kernels
// ---------------------------------------------------------------------------
__global__ void zero_i32_kernel(int* __restrict__ p, int n) {
    int i = blockIdx.x * blockDim.x + threadIdx.x;
    if (i < n) p[i] = 0;
}

// bf16-only residual stream: concat writes hb only
__global__ void concat_kernel(const float* __restrict__ hf, const float* __restrict__ hs,
                              __hip_bfloat16* __restrict__ hb, int Nn) {
    int idx = blockIdx.x * blockDim.x + threadIdx.x;
    int total = Nn * C_DIM;
    if (idx < total) {
        int n = idx >> 8;
        int c = idx & 255;
        float v = (c < HID) ? hf[n * HID + c] : hs[n * HID + (c - HID)];
        hb[idx] = __float2bfloat16(v);
    }
}

// Transpose + convert weights: in [L][K][N] fp32 -> out [L][N][K] bf16
__global__ void transp_bf16_kernel(const float* __restrict__ in,
                                   __hip_bfloat16* __restrict__ out, int K, int N) {
    __shared__ float t[32][33];
    const float* inl = in + (size_t)blockIdx.z * K * N;
    __hip_bfloat16* outl = out + (size_t)blockIdx.z * K * N;
    int kb = blockIdx.y * 32, nb = blockIdx.x * 32;
    int tx = threadIdx.x & 31, ty = threadIdx.x >> 5; // 32x8
    #pragma unroll
    for (int r = 0; r < 32; r += 8)
        t[ty + r][tx] = inl[(size_t)(kb + ty + r) * N + nb + tx];
    __syncthreads();
    #pragma unroll
    for (int r = 0; r < 32; r += 8)
        outl[(size_t)(nb + ty + r) * K + kb + tx] = __float2bfloat16(t[tx][ty + r]);
}

// ---------------------------------------------------------------------------
// CSR build: histogram of dst, exclusive scan (wave-shuffle), fill src lists
// ---------------------------------------------------------------------------
__global__ void hist_kernel(const int* __restrict__ dst, int* __restrict__ counts, int E) {
    int e = blockIdx.x * blockDim.x + threadIdx.x;
    if (e < E) atomicAdd(&counts[dst[e]], 1);
}

// single block, 1024 threads = 16 waves. Wave shuffle scan + serial wave-sum scan.
__global__ void scan_kernel(const int* __restrict__ counts, int* __restrict__ offsets,
                            int* __restrict__ cursor, int n) {
    __shared__ int wsum[16];
    __shared__ int carry_s;
    const int lane = threadIdx.x & 63, wid = threadIdx.x >> 6;
    if (threadIdx.x == 0) carry_s = 0;
    __syncthreads();
    for (int base = 0; base < n; base += 1024) {
        int i = base + (int)threadIdx.x;
        int v = (i < n) ? counts[i] : 0;
        int x = v;
        #pragma unroll
        for (int off = 1; off < 64; off <<= 1) {
            int t = __shfl_up(x, off);
            if (lane >= off) x += t;
        }
        if (lane == 63) wsum[wid] = x;
        __syncthreads();
        if (threadIdx.x == 0) {
            int acc = carry_s;
            #pragma unroll
            for (int w = 0; w < 16; ++w) { int t = wsum[w]; wsum[w] = acc; acc += t; }
            carry_s = acc;
        }
        __syncthreads();
        int excl = wsum[wid] + x - v;
        if (i < n) { offsets[i] = excl; cursor[i] = excl; }
        __syncthreads();
    }
    if (threadIdx.x == 0) offsets[n] = carry_s;
}

__global__ void fill_kernel(const int* __restrict__ src, const int* __restrict__ dst,
                            int* __restrict__ cursor, int* __restrict__ csr_src, int E) {
    int e = blockIdx.x * blockDim.x + threadIdx.x;
    if (e < E) {
        int d = dst[e];
        int p = atomicAdd(&cursor[d], 1);
        csr_src[p] = src[e];
    }
}

// ---------------------------------------------------------------------------
// bf16 MFMA GEMM: 64x64 tile, BK=64, 256 thr (2x2 waves, 32x32 per wave).
// (Plain 2-barrier K-loop: R8's register-prefetch variant measured neutral.)
// C/D: col=lane&15, row=(lane>>4)*4+reg  [verified m89/m91]
// Fused attention epilogue: BN=64 => one block covers one head's columns.
// ---------------------------------------------------------------------------
#define GBM 64
#define GBN 64
#define GBK 64
#define GLS 72   // LDS row stride (shorts): 144B; 2-way bank alias = free

__global__ __launch_bounds__(256) void gemm_bf16_kernel(
    const __hip_bfloat16* __restrict__ A,   // [M x K] bf16 row-major
    const __hip_bfloat16* __restrict__ BT,  // [N x K] bf16 row-major (B^T)
    const float* __restrict__ bias,         // [N] or null
    __hip_bfloat16* __restrict__ Cb,        // bf16 out
    const float* __restrict__ attS,         // [N] att_src slice or null
    const float* __restrict__ attD,
    float* __restrict__ aS,                 // [M x HEADS] out or null
    float* __restrict__ aD,
    int M, int N, int K, int relu)
{
    __shared__ short As[GBM * GLS];
    __shared__ short Bs[GBN * GLS];
    __shared__ float attP[2][2][GBM];       // [wn-half][s|d][row]
    const int tid = threadIdx.x;
    const int wave = tid >> 6, lane = tid & 63;
    const int lr = lane & 15, lq = lane >> 4;
    const int wm = (wave >> 1) * 32, wn = (wave & 1) * 32;
    const int row0 = blockIdx.x * GBM, col0 = blockIdx.y * GBN;

    const int sr = tid >> 2;              // staging row 0..63
    const int sc = (tid & 3) * 16;        // staging col (shorts): 0,16,32,48

    f32x4 acc[2][2] = {};

    for (int k0 = 0; k0 < K; k0 += GBK) {
        int gr = row0 + sr;
        i32x4 va0 = {}, va1 = {};
        if (gr < M) {
            const __hip_bfloat16* ap = &A[(size_t)gr * K + k0 + sc];
            va0 = *(const i32x4*)ap;
            va1 = *(const i32x4*)(ap + 8);
        }
        *(i32x4*)&As[sr * GLS + sc] = va0;
        *(i32x4*)&As[sr * GLS + sc + 8] = va1;
        const __hip_bfloat16* bp = &BT[(size_t)(col0 + sr) * K + k0 + sc];
        *(i32x4*)&Bs[sr * GLS + sc] = *(const i32x4*)bp;
        *(i32x4*)&Bs[sr * GLS + sc + 8] = *(const i32x4*)(bp + 8);
        __syncthreads();

        #pragma unroll
        for (int ks = 0; ks < 2; ++ks) {
            bf16x8_t af[2], bfr[2];
            #pragma unroll
            for (int t = 0; t < 2; ++t) {
                af[t]  = *(const bf16x8_t*)&As[(wm + t * 16 + lr) * GLS + ks * 32 + lq * 8];
                bfr[t] = *(const bf16x8_t*)&Bs[(wn + t * 16 + lr) * GLS + ks * 32 + lq * 8];
            }
            #pragma unroll
            for (int mt = 0; mt < 2; ++mt)
                #pragma unroll
                for (int nt = 0; nt < 2; ++nt)
                    acc[mt][nt] = __builtin_amdgcn_mfma_f32_16x16x32_bf16(
                        af[mt], bfr[nt], acc[mt][nt], 0, 0, 0);
        }
        __syncthreads();
    }

    float bv[2];
    #pragma unroll
    for (int nt = 0; nt < 2; ++nt)
        bv[nt] = bias ? bias[col0 + wn + nt * 16 + lr] : 0.f;

    #pragma unroll
    for (int mt = 0; mt < 2; ++mt) {
        #pragma unroll
        for (int r = 0; r < 4; ++r) {
            int grow = row0 + wm + mt * 16 + lq * 4 + r;
            if (grow >= M) continue;
            #pragma unroll
            for (int nt = 0; nt < 2; ++nt) {
                float v = acc[mt][nt][r] + bv[nt];
                if (relu) v = fmaxf(v, 0.f);
                Cb[(size_t)grow * N + col0 + wn + nt * 16 + lr] = __float2bfloat16(v);
            }
        }
    }

    // Fused attention-coefficient epilogue (gemm1 only)
    if (aS) {
        const int head = col0 >> 6;        // block covers one head (BN=64)
        float atS[2], atD[2];
        #pragma unroll
        for (int nt = 0; nt < 2; ++nt) {
            int c = col0 + wn + nt * 16 + lr;
            atS[nt] = attS[c];
            atD[nt] = attD[c];
        }
        #pragma unroll
        for (int mt = 0; mt < 2; ++mt) {
            #pragma unroll
            for (int r = 0; r < 4; ++r) {
                float vs = acc[mt][0][r] * atS[0] + acc[mt][1][r] * atS[1];
                float vd = acc[mt][0][r] * atD[0] + acc[mt][1][r] * atD[1];
                #pragma unroll
                for (int off = 1; off < 16; off <<= 1) {
                    vs += __shfl_xor(vs, off);
                    vd += __shfl_xor(vd, off);
                }
                if (lr == 0) {
                    int rl = wm + mt * 16 + lq * 4 + r;
                    attP[wave & 1][0][rl] = vs;
                    attP[wave & 1][1][rl] = vd;
                }
            }
        }
        __syncthreads();
        if (tid < GBM) {
            int grow = row0 + tid;
            if (grow < M) {
                aS[grow * HEADS + head] = attP[0][0][tid] + attP[1][0][tid];
                aD[grow * HEADS + head] = attP[0][1][tid] + attP[1][1][tid];
            }
        }
    }
}

// ---------------------------------------------------------------------------
// Fused GAT: per-edge exp weights in-loop + weighted bf16 gather + bias +
// residual (bf16 hb) + LN1. One WAVE per node; lane owns 8 channels (16B
// gathers); two 32-lane halves process disjoint edge halves; combined via
// shfl_xor(32). hb updated in place (bf16-only residual stream).
// ---------------------------------------------------------------------------
__global__ __launch_bounds__(256) void agg_kernel(
    const __hip_bfloat16* __restrict__ xhb, const float* __restrict__ a_s,
    const float* __restrict__ a_d, const int* __restrict__ csr,
    const int* __restrict__ offs, const float* __restrict__ gat_b,
    const float* __restrict__ ln_g, const float* __restrict__ ln_b,
    __hip_bfloat16* __restrict__ hb, int Nn)
{
    const int lane = threadIdx.x & 63;
    const int n = __builtin_amdgcn_readfirstlane(blockIdx.x * 4 + (threadIdx.x >> 6));
    if (n >= Nn) return;
    const int half = lane >> 5;
    const int sl = lane & 31;
    const int head = sl >> 3;            // 8 lanes per head
    const int c0 = sl * 8;               // 8 channels per lane
    const unsigned* x = (const unsigned*)xhb;   // packed bf16 pairs
    const size_t rowp = (size_t)n * (C_DIM / 2) + (c0 >> 1);

    const float ad = a_d[n * 4 + head];

    const int beg = offs[n], end = offs[n + 1];
    const int ne = end - beg;
    const int nh0 = (ne + 1) >> 1;
    int ih  = half ? (beg + nh0) : beg;
    int cnt = half ? (ne - nh0) : nh0;

    // residual from bf16 hb (issue early)
    i32x4 rv = *(const i32x4*)&((const unsigned*)hb)[rowp];

    float acc[8] = {};
    float z = 0.f;

    {
        float wself = __expf(leaky(a_s[n * 4 + head] + ad));
        if (half) {
            i32x4 xv = *(const i32x4*)&x[rowp];
            #pragma unroll
            for (int q = 0; q < 4; ++q) {
                float lo, hi; bf2x((unsigned)xv[q], lo, hi);
                acc[2 * q]     = wself * lo;
                acc[2 * q + 1] = wself * hi;
            }
            z = wself;
        }
    }

    for (; cnt >= 4; cnt -= 4, ih += 4) {
        int s0 = csr[ih], s1 = csr[ih + 1], s2 = csr[ih + 2], s3 = csr[ih + 3];
        float w0 = __expf(leaky(a_s[s0 * 4 + head] + ad));
        float w1 = __expf(leaky(a_s[s1 * 4 + head] + ad));
        float w2 = __expf(leaky(a_s[s2 * 4 + head] + ad));
        float w3 = __expf(leaky(a_s[s3 * 4 + head] + ad));
        i32x4 x0 = *(const i32x4*)&x[(size_t)s0 * (C_DIM / 2) + (c0 >> 1)];
        i32x4 x1 = *(const i32x4*)&x[(size_t)s1 * (C_DIM / 2) + (c0 >> 1)];
        i32x4 x2 = *(const i32x4*)&x[(size_t)s2 * (C_DIM / 2) + (c0 >> 1)];
        i32x4 x3 = *(const i32x4*)&x[(size_t)s3 * (C_DIM / 2) + (c0 >> 1)];
        #pragma unroll
        for (int q = 0; q < 4; ++q) {
            float lo, hi;
            bf2x((unsigned)x0[q], lo, hi);
            acc[2 * q] += w0 * lo; acc[2 * q + 1] += w0 * hi;
            bf2x((unsigned)x1[q], lo, hi);
            acc[2 * q] += w1 * lo; acc[2 * q + 1] += w1 * hi;
            bf2x((unsigned)x2[q], lo, hi);
            acc[2 * q] += w2 * lo; acc[2 * q + 1] += w2 * hi;
            bf2x((unsigned)x3[q], lo, hi);
            acc[2 * q] += w3 * lo; acc[2 * q + 1] += w3 * hi;
        }
        z += (w0 + w1) + (w2 + w3);
    }
    for (; cnt > 0; --cnt, ++ih) {
        int s0 = csr[ih];
        float w0 = __expf(leaky(a_s[s0 * 4 + head] + ad));
        i32x4 x0 = *(const i32x4*)&x[(size_t)s0 * (C_DIM / 2) + (c0 >> 1)];
        #pragma unroll
        for (int q = 0; q < 4; ++q) {
            float lo, hi; bf2x((unsigned)x0[q], lo, hi);
            acc[2 * q] += w0 * lo; acc[2 * q + 1] += w0 * hi;
        }
        z += w0;
    }

    #pragma unroll
    for (int j = 0; j < 8; ++j) acc[j] += __shfl_xor(acc[j], 32);
    z += __shfl_xor(z, 32);

    float res[8];
    #pragma unroll
    for (int q = 0; q < 4; ++q) bf2x((unsigned)rv[q], res[2 * q], res[2 * q + 1]);

    float4 gb0 = *(const float4*)&gat_b[c0];
    float4 gb1 = *(const float4*)&gat_b[c0 + 4];
    float gb[8] = {gb0.x, gb0.y, gb0.z, gb0.w, gb1.x, gb1.y, gb1.z, gb1.w};
    float rz = 1.0f / z;
    float val[8];
    #pragma unroll
    for (int j = 0; j < 8; ++j) val[j] = acc[j] * rz + gb[j] + res[j];

    // LN: each channel appears on 2 lanes -> normalize by 512.
    float s1 = 0.f, s2 = 0.f;
    #pragma unroll
    for (int j = 0; j < 8; ++j) { s1 += val[j]; s2 += val[j] * val[j]; }
    #pragma unroll
    for (int off = 1; off < 64; off <<= 1) {
        s1 += __shfl_xor(s1, off);
        s2 += __shfl_xor(s2, off);
    }
    float mean = s1 * (1.0f / (2 * C_DIM));
    float inv = rsqrtf(s2 * (1.0f / (2 * C_DIM)) - mean * mean + LN_EPS);

    if (half == 0) {
        float4 g0 = *(const float4*)&ln_g[c0];
        float4 g1 = *(const float4*)&ln_g[c0 + 4];
        float4 bb0 = *(const float4*)&ln_b[c0];
        float4 bb1 = *(const float4*)&ln_b[c0 + 4];
        float g[8] = {g0.x, g0.y, g0.z, g0.w, g1.x, g1.y, g1.z, g1.w};
        float bb[8] = {bb0.x, bb0.y, bb0.z, bb0.w, bb1.x, bb1.y, bb1.z, bb1.w};
        float o[8];
        #pragma unroll
        for (int j = 0; j < 8; ++j) o[j] = (val[j] - mean) * inv * g[j] + bb[j];
        i32x4 ob;
        ob[0] = (int)packbf(o[0], o[1]);
        ob[1] = (int)packbf(o[2], o[3]);
        ob[2] = (int)packbf(o[4], o[5]);
        ob[3] = (int)packbf(o[6], o[7]);
        *(i32x4*)&((unsigned*)hb)[rowp] = ob;
    }
}

// ---------------------------------------------------------------------------
// ln2: val = bf2f(fb) + bf2f(hb); LN; writes hb, or (final layer) split fp32.
// ---------------------------------------------------------------------------
__global__ __launch_bounds__(256) void ln2_kernel(
    const __hip_bfloat16* __restrict__ fb, const float* __restrict__ ln_g,
    const float* __restrict__ ln_b, __hip_bfloat16* __restrict__ hb,
    float* __restrict__ out_split, int Nn)
{
    const int lane = threadIdx.x & 63;
    const int n = __builtin_amdgcn_readfirstlane(blockIdx.x * 4 + (threadIdx.x >> 6));
    if (n >= Nn) return;
    const int c0 = lane * 4;
    const unsigned short* f = (const unsigned short*)fb;
    const unsigned short* r = (const unsigned short*)hb;

    ushort4 rv = *(const ushort4*)&r[(size_t)n * C_DIM + c0];
    ushort4 fv = *(const ushort4*)&f[(size_t)n * C_DIM + c0];
    float val[4];
    val[0] = bf2f(fv.x) + bf2f(rv.x);
    val[1] = bf2f(fv.y) + bf2f(rv.y);
    val[2] = bf2f(fv.z) + bf2f(rv.z);
    val[3] = bf2f(fv.w) + bf2f(rv.w);

    float s1 = (val[0] + val[1]) + (val[2] + val[3]);
    float s2 = (val[0] * val[0] + val[1] * val[1]) + (val[2] * val[2] + val[3] * val[3]);
    #pragma unroll
    for (int off = 1; off < 64; off <<= 1) {
        s1 += __shfl_xor(s1, off);
        s2 += __shfl_xor(s2, off);
    }
    float mean = s1 * (1.0f / C_DIM);
    float inv = rsqrtf(s2 * (1.0f / C_DIM) - mean * mean + LN_EPS);
    float4 g = *(const float4*)&ln_g[c0];
    float4 bb = *(const float4*)&ln_b[c0];
    float4 o;
    o.x = (val[0] - mean) * inv * g.x + bb.x;
    o.y = (val[1] - mean) * inv * g.y + bb.y;
    o.z = (val[2] - mean) * inv * g.z + bb.z;
    o.w = (val[3] - mean) * inv * g.w + bb.w;

    if (out_split) {
        size_t off_ = (c0 < HID) ? ((size_t)n * HID + c0)
                                 : ((size_t)Nn * HID + (size_t)n * HID + (c0 - HID));
        *(float4*)&out_split[off_] = o;
    } else {
        ushort4 ob;
        ob.x = __bfloat16_as_ushort(__float2bfloat16(o.x));
        ob.y = __bfloat16_as_ushort(__float2bfloat16(o.y));
        ob.z = __bfloat16_as_ushort(__float2bfloat16(o.z));
        ob.w = __bfloat16_as_ushort(__float2bfloat16(o.w));
        *(ushort4*)&((unsigned short*)hb)[(size_t)n * C_DIM + c0] = ob;
    }
}

// ---------------------------------------------------------------------------
// Host launch
// ---------------------------------------------------------------------------
extern "C" void kernel_launch(void* const* d_in, const int* in_sizes, int n_in,
                              void* d_out, int out_size, void* d_ws, size_t ws_size,
                              hipStream_t stream)
{
    const float* hf       = (const float*)d_in[0];
    const float* hs       = (const float*)d_in[1];
    const int*   edge     = (const int*)  d_in[2];
    const float* W        = (const float*)d_in[3];
    const float* att_src  = (const float*)d_in[4];
    const float* att_dst  = (const float*)d_in[5];
    const float* gat_b    = (const float*)d_in[6];
    const float* w1       = (const float*)d_in[7];
    const float* b1       = (const float*)d_in[8];
    const float* w2       = (const float*)d_in[9];
    const float* b2       = (const float*)d_in[10];
    const float* ln1g     = (const float*)d_in[11];
    const float* ln1b     = (const float*)d_in[12];
    const float* ln2g     = (const float*)d_in[13];
    const float* ln2b     = (const float*)d_in[14];
    float* out = (float*)d_out;

    const int N = in_sizes[0] / HID;       // 20000
    const int E = in_sizes[2] / 2;         // 320000
    const int* e_src = edge;
    const int* e_dst = edge + E;

    char* p = (char*)d_ws;
    auto alloc = [&](size_t bytes) {
        char* r = p;
        p += (bytes + 255) & ~(size_t)255;
        return (void*)r;
    };
    __hip_bfloat16* hb     = (__hip_bfloat16*)alloc((size_t)N * C_DIM * 2);
    __hip_bfloat16* xhb    = (__hip_bfloat16*)alloc((size_t)N * C_DIM * 2);  // gemm1 out
    __hip_bfloat16* fbuf   = (__hip_bfloat16*)alloc((size_t)N * C_DIM * 2);  // gemm3 out
    __hip_bfloat16* midb   = (__hip_bfloat16*)alloc((size_t)N * FF_DIM * 2);
    float*          a_s    = (float*)alloc((size_t)N * HEADS * 4);
    float*          a_d    = (float*)alloc((size_t)N * HEADS * 4);
    int*            counts = (int*)alloc((size_t)N * 4);
    int*            offs   = (int*)alloc((size_t)(N + 1) * 4);
    int*            cursor = (int*)alloc((size_t)N * 4);
    int*            csr    = (int*)alloc((size_t)E * 4);
    __hip_bfloat16* WT     = (__hip_bfloat16*)alloc((size_t)NLAYERS * C_DIM * C_DIM * 2);
    __hip_bfloat16* w1T    = (__hip_bfloat16*)alloc((size_t)NLAYERS * C_DIM * FF_DIM * 2);
    __hip_bfloat16* w2T    = (__hip_bfloat16*)alloc((size_t)NLAYERS * FF_DIM * C_DIM * 2);

    {
        int total = N * C_DIM;
        concat_kernel<<<(total + 255) / 256, 256, 0, stream>>>(hf, hs, hb, N);
    }
    transp_bf16_kernel<<<dim3(C_DIM / 32, C_DIM / 32, NLAYERS), 256, 0, stream>>>(W, WT, C_DIM, C_DIM);
    transp_bf16_kernel<<<dim3(FF_DIM / 32, C_DIM / 32, NLAYERS), 256, 0, stream>>>(w1, w1T, C_DIM, FF_DIM);
    transp_bf16_kernel<<<dim3(C_DIM / 32, FF_DIM / 32, NLAYERS), 256, 0, stream>>>(w2, w2T, FF_DIM, C_DIM);

    zero_i32_kernel<<<(N + 255) / 256, 256, 0, stream>>>(counts, N);
    hist_kernel<<<(E + 255) / 256, 256, 0, stream>>>(e_dst, counts, E);
    scan_kernel<<<1, 1024, 0, stream>>>(counts, offs, cursor, N);
    fill_kernel<<<(E + 255) / 256, 256, 0, stream>>>(e_src, e_dst, cursor, csr, E);

    const int gm = (N + GBM - 1) / GBM;   // 313

    for (int l = 0; l < NLAYERS; ++l) {
        const __hip_bfloat16* Wl  = WT  + (size_t)l * C_DIM * C_DIM;
        const __hip_bfloat16* w1l = w1T + (size_t)l * C_DIM * FF_DIM;
        const __hip_bfloat16* w2l = w2T + (size_t)l * FF_DIM * C_DIM;
        const float* asl  = att_src + (size_t)l * C_DIM;
        const float* adl  = att_dst + (size_t)l * C_DIM;
        const float* gbl  = gat_b + (size_t)l * C_DIM;
        const float* b1l  = b1 + (size_t)l * FF_DIM;
        const float* b2l  = b2 + (size_t)l * C_DIM;
        const float* g1l  = ln1g + (size_t)l * C_DIM;
        const float* be1l = ln1b + (size_t)l * C_DIM;
        const float* g2l  = ln2g + (size_t)l * C_DIM;
        const float* be2l = ln2b + (size_t)l * C_DIM;

        // xhb = hb @ W[l] (bf16 out) + fused a_s/a_d epilogue
        gemm_bf16_kernel<<<dim3(gm, C_DIM / GBN), 256, 0, stream>>>(
            hb, Wl, nullptr, xhb, asl, adl, a_s, a_d, N, C_DIM, C_DIM, 0);
        // fused exp-weights + softmax-agg + bias + residual + LN1 (hb in place)
        agg_kernel<<<(N + 3) / 4, 256, 0, stream>>>(
            xhb, a_s, a_d, csr, offs, gbl, g1l, be1l, hb, N);
        // mid = relu(hb @ w1 + b1)  (bf16 out)
        gemm_bf16_kernel<<<dim3(gm, FF_DIM / GBN), 256, 0, stream>>>(
            hb, w1l, b1l, midb, nullptr, nullptr, nullptr, nullptr,
            N, FF_DIM, C_DIM, 1);
        // fbuf = mid @ w2 + b2  (bf16 out)
        gemm_bf16_kernel<<<dim3(gm, C_DIM / GBN), 256, 0, stream>>>(
            midb, w2l, b2l, fbuf, nullptr, nullptr, nullptr, nullptr,
            N, C_DIM, FF_DIM, 0);
        // hb = LN(fbuf + hb); final layer writes split output directly
        ln2_kernel<<<(N + 3) / 4, 256, 0, stream>>>(
            fbuf, g2l, be2l, hb, (l == NLAYERS - 1) ? out : nullptr, N);
    }
}